// Round 1
// baseline (213.975 us; speedup 1.0000x reference)
//
#include <hip/hip_runtime.h>
#include <hip/hip_fp16.h>
#include <cfloat>
#include <math.h>

// Problem constants (fixed by the reference)
#define DIM    256
#define N_TOK  8192
#define N_E    8192
#define NSEG   1024         // 8-col groups per row
// Margin on d = ||e||^2 - 2*dot (bf16 approx pass, fp16-quantized group mins).
// Failure needs Dd(true)-Dd(approx-winner) + 2*quant > margin on a specific
// per-row pair: dot-err diff ~4.3sigma*6.8e-4 ~2.9e-3, fp16 quant 2*1e-3.
// 0.012 ~ 2.4x that. (Passed rounds 7-10; 0.016 and 0.008 also passed.)
#define MARGIN 0.012f

typedef __attribute__((ext_vector_type(8))) short bf16x8;
typedef __attribute__((ext_vector_type(4))) float f32x4;
typedef __attribute__((ext_vector_type(8))) unsigned short ushort8;

__device__ __forceinline__ unsigned short f2bf(float f) {      // RNE float->bf16
    unsigned u = __float_as_uint(f);
    unsigned r = u + 0x7fff + ((u >> 16) & 1);
    return (unsigned short)(r >> 16);
}
__device__ __forceinline__ unsigned fkey(float f) {            // monotone f32->u32
    unsigned u = __float_as_uint(f);
    return (u & 0x80000000u) ? ~u : (u | 0x80000000u);
}
__device__ __forceinline__ unsigned short f2h(float f) {       // RNE float->fp16 bits
    const __half h = __float2half(f);
    return *(const unsigned short*)&h;
}
__device__ __forceinline__ float h2f(unsigned short u) {
    __half_raw r; r.x = u;
    return __half2float((__half)r);
}

// ---------------------------------------------------------------------------
// K1: row-wise L2 normalize for BOTH inputs in one launch.
//  - z rows   -> zn fp32 (d_out scratch) + zb bf16 PLAIN row-major.
//  - emb rows -> en fp32 + esw bf16 swizzled into exact MFMA A-fragment order
//    (frag16=row>>4, kc: 512 ushorts at (frag16*8+kc)*512; within:
//    ((k>>3&3)*16 + (row&15))*8 + (k&7)) + e2.
// ---------------------------------------------------------------------------
__global__ __launch_bounds__(256) void l2norm_all(const float* __restrict__ z,
                                                  const float* __restrict__ emb,
                                                  float* __restrict__ zn,
                                                  unsigned short* __restrict__ zb,
                                                  float* __restrict__ en,
                                                  unsigned short* __restrict__ esw,
                                                  float* __restrict__ e2) {
    const int lane = threadIdx.x & 63;
    const bool isE = blockIdx.x < (N_E / 4);
    const int row = (isE ? blockIdx.x : blockIdx.x - N_E / 4) * 4 + (threadIdx.x >> 6);
    const float* in = isE ? emb : z;
    float* out = isE ? en : zn;
    const float4 v = *(const float4*)(in + row * DIM + lane * 4);
    float s = v.x * v.x + v.y * v.y + v.z * v.z + v.w * v.w;
#pragma unroll
    for (int off = 1; off < 64; off <<= 1) s += __shfl_xor(s, off, 64);
    const float inv = 1.0f / fmaxf(sqrtf(s), 1e-12f);
    const float4 o = make_float4(v.x * inv, v.y * inv, v.z * inv, v.w * inv);
    *(float4*)(out + row * DIM + lane * 4) = o;
    ushort4 ob; ob.x = f2bf(o.x); ob.y = f2bf(o.y); ob.z = f2bf(o.z); ob.w = f2bf(o.w);
    const int k0 = lane * 4;
    if (isE) {
        const size_t sidx = ((size_t)((row >> 4) * 8 + (k0 >> 5)) * 64
                             + ((k0 >> 3) & 3) * 16 + (row & 15)) * 8 + (k0 & 7);
        *(ushort4*)(esw + sidx) = ob;
        float q = o.x * o.x + o.y * o.y + o.z * o.z + o.w * o.w;
#pragma unroll
        for (int off = 1; off < 64; off <<= 1) q += __shfl_xor(q, off, 64);
        if (lane == 0) e2[row] = q;
    } else {
        *(ushort4*)(zb + (size_t)row * DIM + k0) = ob;
    }
}

// ---------------------------------------------------------------------------
// K2: bf16 MFMA distance pass, v2 — stage-once / barrier-once structure.
// Block = 128 z-rows x 512 codes, processed as 4 col-tiles of 128.
// Grid 64x16 = 1024 blocks; 56 KB LDS -> 2 resident blocks/CU, 4 sequential.
//  - z rows kc 0..5 staged ONCE in kc-major As[kc][128][32] (48 KB): staging
//    is linear global_load_lds dwordx4 (contiguous 64 B per row on the global
//    side, linear LDS dst); fragment ds_read_b128 = base + immediate offset,
//    8 lanes per bank-quad (balanced -> the same 0-conflict pattern as v1).
//  - z fragments for kc 6,7 loaded once into registers (32 VGPR), reused by
//    all 4 tiles; squeezes As under the 64 KB static limit w/ the smw pads.
//  - ONE __syncthreads total. Epilogue transpose uses a per-wave private
//    smw[8][64] pad (write conflict-free, read 2-way/free), so waves never
//    re-sync: epilogue VALU of one wave overlaps MFMA of the others.
//  - code fragments: rolling 2-kc register prefetch from frag-order esw;
//    next tile's ca[0]/ca[1] issued during the register-only kc=6/7 steps,
//    so no per-tile cold start.
// Numerics identical to v1 (same kc order, same inputs) -> MARGIN unchanged.
// ---------------------------------------------------------------------------
__global__ __launch_bounds__(256, 2) void mfma_dist(const unsigned short* __restrict__ zb,
                                                    const unsigned short* __restrict__ esw,
                                                    const float* __restrict__ e2,
                                                    unsigned short* __restrict__ segMh) {
    __shared__ __align__(16) unsigned short As[6][128][32];   // 48 KB z (kc-major)
    __shared__ float smw[4][8][64];                           //  8 KB per-wave pads

    const int tid  = threadIdx.x;
    const int lane = tid & 63;
    const int wave = tid >> 6;
    const int wm = wave & 1, wn = wave >> 1;
    const int rb = blockIdx.x & 63;          // row block (128 rows)
    const int cb = blockIdx.x >> 6;          // col group (512 codes)
    const int row0 = rb * 128;
    const int fr = lane & 15, q = lane >> 4;

    // ---- prologue: issue everything, then the single barrier ----
    // Code fragments, frag-order esw: frag16 = cb*32 + ct*8 + wn*4 + i
    const unsigned short* ebase = esw + (size_t)(cb * 32 + wn * 4) * 4096 + lane * 8;
    auto la = [&](int ct, int i, int kc) {
        return *(const bf16x8*)(ebase + (size_t)(ct * 8 + i) * 4096 + kc * 512);
    };
    bf16x8 ca[8][4];
#pragma unroll
    for (int i = 0; i < 4; i++) ca[0][i] = la(0, i, 0);
#pragma unroll
    for (int i = 0; i < 4; i++) ca[1][i] = la(0, i, 1);

    // z fragments kc=6,7 -> registers, reused across all 4 tiles.
    // Same bytes the v1 LDS path delivered: row (wm*64+i*16+fr), k = kc*32+q*8.
    bf16x8 z67[2][4];
#pragma unroll
    for (int h = 0; h < 2; h++)
#pragma unroll
        for (int i = 0; i < 4; i++)
            z67[h][i] = *(const bf16x8*)(zb + (size_t)(row0 + wm * 64 + i * 16 + fr) * DIM
                                         + (6 + h) * 32 + q * 8);

    // Stage kc 0..5: 48 x 1KB instrs (12/wave). Instr (kc,h): lane l ->
    // LDS As[kc][h*16 + (l>>2)][(l&3)*8] == linear base + 16*l; global side is
    // 64 B contiguous per row (16 fully-used lines per instr).
#pragma unroll
    for (int jj = 0; jj < 12; jj++) {
        const int idx = wave * 12 + jj;
        const int kc = idx >> 3, h = idx & 7;
        __builtin_amdgcn_global_load_lds(
            (const __attribute__((address_space(1))) unsigned int*)
                (zb + (size_t)(row0 + h * 16 + (lane >> 2)) * DIM + kc * 32 + (lane & 3) * 8),
            (__attribute__((address_space(3))) unsigned int*)&As[kc][h * 16][0],
            16, 0, 0);
    }
    __syncthreads();                          // the ONLY block barrier

    // z fragment read: byte = kc*8192 + row*64 + q*16 -> immediate ds offsets
    const unsigned short* zbase = (const unsigned short*)As + (wm * 64 + fr) * 32 + q * 8;
    auto lz = [&](int i, int kc) {
        return *(const bf16x8*)(zbase + kc * 4096 + i * 512);
    };

    for (int ct = 0; ct < 4; ++ct) {
        float4 e2q[4];                        // epilogue data, issued early
#pragma unroll
        for (int ci = 0; ci < 4; ci++)
            e2q[ci] = *(const float4*)&e2[cb * 512 + ct * 128 + wn * 64 + ci * 16 + q * 4];

        f32x4 acc[4][4];
#pragma unroll
        for (int ci = 0; ci < 4; ci++)
#pragma unroll
            for (int zi = 0; zi < 4; zi++) acc[ci][zi] = (f32x4){0.f, 0.f, 0.f, 0.f};

#pragma unroll
        for (int kc = 0; kc < 6; kc++) {
#pragma unroll
            for (int i = 0; i < 4; i++) ca[kc + 2][i] = la(ct, i, kc + 2);   // window <= 3
            bf16x8 zfr[4];
#pragma unroll
            for (int i = 0; i < 4; i++) zfr[i] = lz(i, kc);
#pragma unroll
            for (int ci = 0; ci < 4; ci++)
#pragma unroll
                for (int zi = 0; zi < 4; zi++)
                    acc[ci][zi] = __builtin_amdgcn_mfma_f32_16x16x32_bf16(ca[kc][ci], zfr[zi], acc[ci][zi], 0, 0, 0);
        }
        // kc 6,7: pure-register MFMA steps; hide next tile's ca[0..1] under them
        if (ct < 3) {
#pragma unroll
            for (int i = 0; i < 4; i++) ca[0][i] = la(ct + 1, i, 0);
        }
#pragma unroll
        for (int ci = 0; ci < 4; ci++)
#pragma unroll
            for (int zi = 0; zi < 4; zi++)
                acc[ci][zi] = __builtin_amdgcn_mfma_f32_16x16x32_bf16(ca[6][ci], z67[0][zi], acc[ci][zi], 0, 0, 0);
        if (ct < 3) {
#pragma unroll
            for (int i = 0; i < 4; i++) ca[1][i] = la(ct + 1, i, 1);
        }
#pragma unroll
        for (int ci = 0; ci < 4; ci++)
#pragma unroll
            for (int zi = 0; zi < 4; zi++)
                acc[ci][zi] = __builtin_amdgcn_mfma_f32_16x16x32_bf16(ca[7][ci], z67[1][zi], acc[ci][zi], 0, 0, 0);

        // Per-wave epilogue (no barrier). C/D: m(code)=(lane>>4)*4+reg, n(z)=lane&15.
#pragma unroll
        for (int ci = 0; ci < 4; ci++) {
#pragma unroll
            for (int zi = 0; zi < 4; zi++) {
                const float t0 = fmaf(-2.0f, acc[ci][zi][0], e2q[ci].x);
                const float t1 = fmaf(-2.0f, acc[ci][zi][1], e2q[ci].y);
                const float t2 = fmaf(-2.0f, acc[ci][zi][2], e2q[ci].z);
                const float t3 = fmaf(-2.0f, acc[ci][zi][3], e2q[ci].w);
                float mm = fminf(fminf(t0, t1), fminf(t2, t3));   // min over 4 codes
                mm = fminf(mm, __shfl_xor(mm, 16, 64));           // pair quads: 8-code min
                if (q == 0) smw[wave][ci * 2 + 0][zi * 16 + fr] = mm;   // even seg
                if (q == 2) smw[wave][ci * 2 + 1][zi * 16 + fr] = mm;   // odd  seg
            }
        }
        // Transpose out of the wave-private pad: lane = row, 8 segs -> ushort8.
        ushort8 o8;
#pragma unroll
        for (int j = 0; j < 8; j++) o8[j] = f2h(smw[wave][j][lane]);
        *(ushort8*)&segMh[(size_t)(row0 + wm * 64 + lane) * NSEG + cb * 64 + ct * 16 + wn * 8] = o8;
    }
}

// ---------------------------------------------------------------------------
// K3 (fused select+rescore+gather): one WAVE per row, ZERO atomics.
//  1. read 1024 fp16 group-mins (2 KB contiguous), shuffle-min -> threshold
//  2. ballot-flag 8-col groups within m+MARGIN (winner always self-flags)
//  3. wave-uniform bit-walk; exact fp32 rescore (16 lanes split the 256-dim
//     dot, 4 cols per pass, 2 passes/group); packed (key|col) running min
//     -> exact argmin with lowest-index tie-break (matches jnp.argmin)
//  4. gather en[idx] -> z_q, per-row loss partial to pl[row], index out.
// ---------------------------------------------------------------------------
__global__ __launch_bounds__(256) void select_rescore(const unsigned short* __restrict__ segMh,
                                                      const float* __restrict__ en,
                                                      const float* __restrict__ e2,
                                                      float* zq,        // d_out: z_norm in / z_q out
                                                      float* out_base,  // d_out
                                                      float* __restrict__ pl) {
    const int lane = threadIdx.x & 63;
    const int row  = (blockIdx.x << 2) + (threadIdx.x >> 6);
    const unsigned short* ph = segMh + (size_t)row * NSEG + lane * 16;
    const ushort8 u0 = *(const ushort8*)ph;
    const ushort8 u1 = *(const ushort8*)(ph + 8);
    float vv[16];
#pragma unroll
    for (int j = 0; j < 8; j++) { vv[j] = h2f(u0[j]); vv[8 + j] = h2f(u1[j]); }
    float m = vv[0];
#pragma unroll
    for (int j = 1; j < 16; j++) m = fminf(m, vv[j]);
#pragma unroll
    for (int off = 1; off < 64; off <<= 1) m = fminf(m, __shfl_xor(m, off, 64));
    const float thr = m + MARGIN;

    // z row in 16-lane-split layout for the rescore dots (shared by all groups)
    const int q = lane >> 4, f = lane & 15;
    const float4* zp = (const float4*)(zq + (size_t)row * DIM);
    float4 z4[4];
#pragma unroll
    for (int j = 0; j < 4; j++) z4[j] = zp[j * 16 + f];

    unsigned long long pk = ~0ull;
#pragma unroll
    for (int j = 0; j < 16; j++) {
        unsigned long long bal = __ballot(vv[j] <= thr);   // wave-uniform
        while (bal) {
            const int l = __ffsll(bal) - 1;
            bal &= bal - 1;
            const int seg = l * 16 + j;                    // lane l holds segs l*16+j
#pragma unroll
            for (int g = 0; g < 2; g++) {
                const int col = seg * 8 + g * 4 + q;
                const float4* ep = (const float4*)(en + (size_t)col * DIM);
                float s = 0.f;
#pragma unroll
                for (int jj = 0; jj < 4; jj++) {
                    const float4 ev = ep[jj * 16 + f];
                    s = fmaf(z4[jj].x, ev.x, s); s = fmaf(z4[jj].y, ev.y, s);
                    s = fmaf(z4[jj].z, ev.z, s); s = fmaf(z4[jj].w, ev.w, s);
                }
#pragma unroll
                for (int off = 1; off < 16; off <<= 1) s += __shfl_xor(s, off, 64);
                const float d = fmaf(-2.0f, s, e2[col]);
                const unsigned long long key =
                    ((unsigned long long)fkey(d) << 32) | (unsigned)col;
                if (key < pk) pk = key;
            }
        }
    }
#pragma unroll
    for (int off = 16; off < 64; off <<= 1) {               // merge the 4 quads
        const unsigned long long o = __shfl_xor(pk, off, 64);
        if (o < pk) pk = o;
    }
    const int i = (int)(pk & 0xffffffffu);

    // Gather z_q, loss partial, index (plain stores, no atomics).
    const float4 qv = *(const float4*)(en + (size_t)i * DIM + lane * 4);
    const float4 zv = *(const float4*)(zq + (size_t)row * DIM + lane * 4);
    const float dx = qv.x - zv.x, dy = qv.y - zv.y, dz = qv.z - zv.z, dw = qv.w - zv.w;
    float s = dx * dx + dy * dy + dz * dz + dw * dw;
    *(float4*)(zq + (size_t)row * DIM + lane * 4) = qv;
#pragma unroll
    for (int off = 1; off < 64; off <<= 1) s += __shfl_xor(s, off, 64);
    if (lane == 0) {
        pl[row] = s;
        out_base[N_TOK * DIM + 1 + row] = (float)i;
    }
}

// ---------------------------------------------------------------------------
// K4: reduce 8192 per-row loss partials -> loss = 1.25 * sum / (8*1024*256).
// ---------------------------------------------------------------------------
__global__ __launch_bounds__(1024) void finalize_loss(const float* __restrict__ pl,
                                                      float* __restrict__ out) {
    __shared__ float sw[16];
    const int t = threadIdx.x;
    float s = 0.f;
#pragma unroll
    for (int j = 0; j < 8; j++) s += pl[t + j * 1024];
#pragma unroll
    for (int off = 1; off < 64; off <<= 1) s += __shfl_xor(s, off, 64);
    if ((t & 63) == 0) sw[t >> 6] = s;
    __syncthreads();
    if (t < 16) {
        float v = sw[t];
#pragma unroll
        for (int off = 1; off < 16; off <<= 1) v += __shfl_xor(v, off, 64);
        if (t == 0) out[N_TOK * DIM] = v * (1.25f / 2097152.0f);
    }
}

// ---------------------------------------------------------------------------
extern "C" void kernel_launch(void* const* d_in, const int* in_sizes, int n_in,
                              void* d_out, int out_size, void* d_ws, size_t ws_size,
                              hipStream_t stream) {
    const float* z   = (const float*)d_in[0];   // [8,1024,256] fp32
    const float* emb = (const float*)d_in[1];   // [8192,256] fp32
    float* out = (float*)d_out;                 // z_q[2097152] | loss[1] | idx[8192]
    char* ws = (char*)d_ws;

    // ws layout (byte offsets; total ~33.6 MB)
    float*          en    = (float*)(ws);                      //  8 MiB fp32 codes (normalized)
    unsigned short* esw   = (unsigned short*)(ws + 8388608);   //  4 MiB bf16 codes (frag-swizzled)
    unsigned short* zb    = (unsigned short*)(ws + 12582912);  //  4 MiB bf16 z (plain row-major)
    float*          e2    = (float*)(ws + 16777216);           // 32 KiB ||e||^2
    unsigned short* segMh = (unsigned short*)(ws + 16809984);  // 16 MiB fp16 [8192][1024]
    float*          pl    = (float*)(ws + 33587200);           // 32 KiB per-row loss partials

    // 1) normalize both inputs (emb -> en/esw/e2; z -> d_out z_q region + zb)
    l2norm_all<<<(N_E + N_TOK) / 4, 256, 0, stream>>>(z, emb, out, zb, en, esw, e2);
    // 2) bf16 MFMA approx distances (stage-once, 1 barrier, 4 col-tiles/block)
    mfma_dist<<<1024, 256, 0, stream>>>(zb, esw, e2, segMh);
    // 3) fused select + exact rescore + gather (wave per row, no atomics)
    select_rescore<<<N_TOK / 4, 256, 0, stream>>>(segMh, en, e2, out, out, pl);
    // 4) reduce loss partials
    finalize_loss<<<1, 1024, 0, stream>>>(pl, out);
}

// Round 3
// 153.552 us; speedup vs baseline: 1.3935x; 1.3935x over previous
//
#include <hip/hip_runtime.h>
#include <hip/hip_fp16.h>
#include <cfloat>
#include <math.h>

// Problem constants (fixed by the reference)
#define DIM    256
#define N_TOK  8192
#define N_E    8192
#define NSEG   1024         // 8-col groups per row
// Margin on d = ||e||^2 - 2*dot (bf16 approx pass, fp16-quantized group mins).
// Failure needs Dd(true)-Dd(approx-winner) + 2*quant > margin on a specific
// per-row pair: dot-err diff ~4.3sigma*6.8e-4 ~2.9e-3, fp16 quant 2*1e-3.
// 0.012 ~ 2.4x that. (Passed rounds 7-10; 0.016 and 0.008 also passed.)
#define MARGIN 0.012f

typedef __attribute__((ext_vector_type(8))) short bf16x8;
typedef __attribute__((ext_vector_type(4))) float f32x4;
typedef __attribute__((ext_vector_type(8))) unsigned short ushort8;

__device__ __forceinline__ unsigned short f2bf(float f) {      // RNE float->bf16
    unsigned u = __float_as_uint(f);
    unsigned r = u + 0x7fff + ((u >> 16) & 1);
    return (unsigned short)(r >> 16);
}
__device__ __forceinline__ unsigned fkey(float f) {            // monotone f32->u32
    unsigned u = __float_as_uint(f);
    return (u & 0x80000000u) ? ~u : (u | 0x80000000u);
}
__device__ __forceinline__ unsigned short f2h(float f) {       // RNE float->fp16 bits
    const __half h = __float2half(f);
    return *(const unsigned short*)&h;
}
__device__ __forceinline__ float h2f(unsigned short u) {
    __half_raw r; r.x = u;
    return __half2float((__half)r);
}

// ---------------------------------------------------------------------------
// K1: row-wise L2 normalize for BOTH inputs in one launch.
//  - z rows   -> zn fp32 (d_out scratch) + zb bf16 PLAIN row-major (the LDS
//    staging swizzle is applied via per-lane global addresses in mfma_dist).
//  - emb rows -> en fp32 + esw bf16 swizzled into exact MFMA A-fragment order
//    (frag16=row>>4, kc: 512 ushorts at (frag16*8+kc)*512; within:
//    ((k>>3&3)*16 + (row&15))*8 + (k&7)) + e2.
// ---------------------------------------------------------------------------
__global__ __launch_bounds__(256) void l2norm_all(const float* __restrict__ z,
                                                  const float* __restrict__ emb,
                                                  float* __restrict__ zn,
                                                  unsigned short* __restrict__ zb,
                                                  float* __restrict__ en,
                                                  unsigned short* __restrict__ esw,
                                                  float* __restrict__ e2) {
    const int lane = threadIdx.x & 63;
    const bool isE = blockIdx.x < (N_E / 4);
    const int row = (isE ? blockIdx.x : blockIdx.x - N_E / 4) * 4 + (threadIdx.x >> 6);
    const float* in = isE ? emb : z;
    float* out = isE ? en : zn;
    const float4 v = *(const float4*)(in + row * DIM + lane * 4);
    float s = v.x * v.x + v.y * v.y + v.z * v.z + v.w * v.w;
#pragma unroll
    for (int off = 1; off < 64; off <<= 1) s += __shfl_xor(s, off, 64);
    const float inv = 1.0f / fmaxf(sqrtf(s), 1e-12f);
    const float4 o = make_float4(v.x * inv, v.y * inv, v.z * inv, v.w * inv);
    *(float4*)(out + row * DIM + lane * 4) = o;
    ushort4 ob; ob.x = f2bf(o.x); ob.y = f2bf(o.y); ob.z = f2bf(o.z); ob.w = f2bf(o.w);
    const int k0 = lane * 4;
    if (isE) {
        const size_t sidx = ((size_t)((row >> 4) * 8 + (k0 >> 5)) * 64
                             + ((k0 >> 3) & 3) * 16 + (row & 15)) * 8 + (k0 & 7);
        *(ushort4*)(esw + sidx) = ob;
        float q = o.x * o.x + o.y * o.y + o.z * o.z + o.w * o.w;
#pragma unroll
        for (int off = 1; off < 64; off <<= 1) q += __shfl_xor(q, off, 64);
        if (lane == 0) e2[row] = q;
    } else {
        *(ushort4*)(zb + (size_t)row * DIM + k0) = ob;
    }
}

// ---------------------------------------------------------------------------
// K2: bf16 MFMA distance pass, v3 = v1 structure + latency fixes.
// 128x128 block tile, 4 waves of 64x64 (4x4 grid of 16x16x32 MFMAs).
//  - z rows: staged into As[2][128 rows x 8 chunks] (16 KB/buffer), BK=64
//    double-buffered, XOR slot swizzle baked into the PER-LANE GLOBAL
//    addresses of global_load_lds; fragment ds_read_b128 at slot
//    (h*4+q)^(fr&7) -> exactly 8 lanes/16B-slot = conflict-free (v1: 0).
//  - codes (v3 change 1): FULL register preload. All kc 0..5 fragment loads
//    issue in the prologue, kc 6..7 during p=0. Every barrier's implicit
//    vmcnt(0) then drains loads that are >=1 full iteration old -> the
//    per-kc L3-latency stall of the rolling window-3 prefetch is gone.
//    Peak ~145 VGPR + 64 acc < 256 cap (launch_bounds(256,2)) -> no spill.
//  - epilogue (v3 change 2): wave-PRIVATE pad smw[wave][8][64] (+8 KB, no As
//    alias) -> ZERO epilogue barriers; waves retire independently, one
//    block's epilogue VALU overlaps the other's MFMA. (Pad pattern was
//    correctness-validated in the round-1 run.)
//  - e2q (v3 change 3): issued at top of p=3 (~600 cyc before use), and the
//    segMh result stream is stored NONTEMPORAL so the 16 MB output doesn't
//    thrash esw/zb out of L2.
// Numerics identical to v1 (same MFMA order/operands) -> MARGIN unchanged.
// ---------------------------------------------------------------------------
__global__ __launch_bounds__(256, 2) void mfma_dist(const unsigned short* __restrict__ zb,
                                                    const unsigned short* __restrict__ esw,
                                                    const float* __restrict__ e2,
                                                    unsigned short* __restrict__ segMh) {
    __shared__ __align__(16) unsigned short As[2][128 * 64];   // 2 x 16 KB z chunk-pair
    __shared__ float smw[4][8][64];                            // 8 KB per-wave pads

    const int tid  = threadIdx.x;
    const int lane = tid & 63;
    const int wave = tid >> 6;
    const int wm = wave & 1, wn = wave >> 1;
    const int row0 = (blockIdx.x & 63) * 128;
    const int col0 = (blockIdx.x >> 6) * 128;
    const int fr = lane & 15, q = lane >> 4;

    f32x4 acc[4][4];
#pragma unroll
    for (int ci = 0; ci < 4; ci++)
#pragma unroll
        for (int zi = 0; zi < 4; zi++) acc[ci][zi] = (f32x4){0.f, 0.f, 0.f, 0.f};

    // Code fragments: frag16 group aBase+i, address = frag*4096 + kc*512 + lane*8
    const int aBase = (col0 >> 4) + wn * 4;
    auto la = [&](int i, int kc) {
        return *(const bf16x8*)(esw + (size_t)(aBase + i) * 4096 + kc * 512 + lane * 8);
    };
    // z staging, pair p (k in [p*64, p*64+64)): wave stages rows wave*32..+31,
    // 4 instrs of 1 KB; lane -> row (lane>>3) of the 8-row slab, slot lane&7.
    // Global chunk fetched = p*8 + (slot ^ (r&7)); r&7 == (lane>>3)&7 here.
    const int cxor = (lane & 7) ^ ((lane >> 3) & 7);            // const per lane
    const unsigned short* gZ = zb + (size_t)(row0 + wave * 32 + (lane >> 3)) * DIM + cxor * 8;
    auto stage = [&](int buf, int p) {
#pragma unroll
        for (int j = 0; j < 4; j++) {
            __builtin_amdgcn_global_load_lds(
                (const __attribute__((address_space(1))) unsigned int*)(gZ + (size_t)j * 8 * DIM + p * 64),
                (__attribute__((address_space(3))) unsigned int*)&As[buf][(wave * 32 + j * 8) * 64],
                16, 0, 0);
        }
    };
    // z fragment from LDS: kc = 2p+h, logical chunk h*4+q, slot ^= (fr&7).
    auto lz = [&](int buf, int i, int h) {
        const int r = wm * 64 + i * 16 + fr;
        const int slot = (h * 4 + q) ^ (fr & 7);
        return *(const bf16x8*)&As[buf][r * 64 + slot * 8];
    };

    // Prologue: preload kc 0..5 code fragments (24 x 1KB wave-loads, all in
    // flight together; drained once at the p=0 barrier), then stage pair 0.
    bf16x8 ca[8][4];
#pragma unroll
    for (int kc = 0; kc < 6; kc++)
#pragma unroll
        for (int i = 0; i < 4; i++) ca[kc][i] = la(i, kc);
    stage(0, 0);

    float4 e2q[4];

#pragma unroll
    for (int p = 0; p < 4; p++) {
        __syncthreads();                 // drains stage(p) (1 full pair of compute in flight)
        if (p < 3) stage((p + 1) & 1, p + 1);
        if (p == 3) {                    // epilogue data, ~600 cyc before use
#pragma unroll
            for (int ci = 0; ci < 4; ci++)
                e2q[ci] = *(const float4*)&e2[col0 + wn * 64 + ci * 16 + q * 4];
        }
#pragma unroll
        for (int h = 0; h < 2; h++) {
            const int kc = 2 * p + h;
            if (kc < 2) {                // finish the code preload (kc 6,7)
#pragma unroll
                for (int i = 0; i < 4; i++) ca[kc + 6][i] = la(i, kc + 6);
            }
            bf16x8 zfr[4];
#pragma unroll
            for (int i = 0; i < 4; i++) zfr[i] = lz(p & 1, i, h);
#pragma unroll
            for (int ci = 0; ci < 4; ci++)
#pragma unroll
                for (int zi = 0; zi < 4; zi++)
                    acc[ci][zi] = __builtin_amdgcn_mfma_f32_16x16x32_bf16(ca[kc][ci], zfr[zi], acc[ci][zi], 0, 0, 0);
        }
    }

    // Per-wave epilogue, NO barriers. C/D: m (code) = (lane>>4)*4 + reg,
    // n (z row) = lane&15. Cross-lane handoff stays inside the wave; the
    // compiler orders the dependent ds ops (validated in round 1).
#pragma unroll
    for (int ci = 0; ci < 4; ci++) {
#pragma unroll
        for (int zi = 0; zi < 4; zi++) {
            const float t0 = fmaf(-2.0f, acc[ci][zi][0], e2q[ci].x);
            const float t1 = fmaf(-2.0f, acc[ci][zi][1], e2q[ci].y);
            const float t2 = fmaf(-2.0f, acc[ci][zi][2], e2q[ci].z);
            const float t3 = fmaf(-2.0f, acc[ci][zi][3], e2q[ci].w);
            float mm = fminf(fminf(t0, t1), fminf(t2, t3));   // min over 4 codes (regs)
            mm = fminf(mm, __shfl_xor(mm, 16, 64));           // pair quads: 8-code min
            // q==0 holds codes 0..7 min; q==2 holds codes 8..15 min
            if (q == 0) smw[wave][ci * 2 + 0][zi * 16 + fr] = mm;
            if (q == 2) smw[wave][ci * 2 + 1][zi * 16 + fr] = mm;
        }
    }
    // Transpose out of the wave-private pad: lane = local row, 8 segs packed.
    // Nontemporal: 16 MB result stream must not evict esw/zb from L2.
    ushort8 o8;
#pragma unroll
    for (int j = 0; j < 8; j++) o8[j] = f2h(smw[wave][j][lane]);
    __builtin_nontemporal_store(
        o8, (ushort8*)&segMh[(size_t)(row0 + wm * 64 + lane) * NSEG + (col0 >> 3) + wn * 8]);
}

// ---------------------------------------------------------------------------
// K3 (fused select+rescore+gather): one WAVE per row, ZERO atomics.
//  1. read 1024 fp16 group-mins (2 KB contiguous, nontemporal), shuffle-min
//  2. ballot-flag 8-col groups within m+MARGIN (winner always self-flags)
//  3. wave-uniform bit-walk; exact fp32 rescore (16 lanes split the 256-dim
//     dot, 4 cols per pass, 2 passes/group); packed (key|col) running min
//     -> exact argmin with lowest-index tie-break (matches jnp.argmin)
//  4. gather en[idx] -> z_q, per-row loss partial to pl[row], index out.
// ---------------------------------------------------------------------------
__global__ __launch_bounds__(256) void select_rescore(const unsigned short* __restrict__ segMh,
                                                      const float* __restrict__ en,
                                                      const float* __restrict__ e2,
                                                      float* zq,        // d_out: z_norm in / z_q out
                                                      float* out_base,  // d_out
                                                      float* __restrict__ pl) {
    const int lane = threadIdx.x & 63;
    const int row  = (blockIdx.x << 2) + (threadIdx.x >> 6);
    const unsigned short* ph = segMh + (size_t)row * NSEG + lane * 16;
    const ushort8 u0 = __builtin_nontemporal_load((const ushort8*)ph);
    const ushort8 u1 = __builtin_nontemporal_load((const ushort8*)(ph + 8));
    float vv[16];
#pragma unroll
    for (int j = 0; j < 8; j++) { vv[j] = h2f(u0[j]); vv[8 + j] = h2f(u1[j]); }
    float m = vv[0];
#pragma unroll
    for (int j = 1; j < 16; j++) m = fminf(m, vv[j]);
#pragma unroll
    for (int off = 1; off < 64; off <<= 1) m = fminf(m, __shfl_xor(m, off, 64));
    const float thr = m + MARGIN;

    // z row in 16-lane-split layout for the rescore dots (shared by all groups)
    const int q = lane >> 4, f = lane & 15;
    const float4* zp = (const float4*)(zq + (size_t)row * DIM);
    float4 z4[4];
#pragma unroll
    for (int j = 0; j < 4; j++) z4[j] = zp[j * 16 + f];

    unsigned long long pk = ~0ull;
#pragma unroll
    for (int j = 0; j < 16; j++) {
        unsigned long long bal = __ballot(vv[j] <= thr);   // wave-uniform
        while (bal) {
            const int l = __ffsll(bal) - 1;
            bal &= bal - 1;
            const int seg = l * 16 + j;                    // lane l holds segs l*16+j
#pragma unroll
            for (int g = 0; g < 2; g++) {
                const int col = seg * 8 + g * 4 + q;
                const float4* ep = (const float4*)(en + (size_t)col * DIM);
                float s = 0.f;
#pragma unroll
                for (int jj = 0; jj < 4; jj++) {
                    const float4 ev = ep[jj * 16 + f];
                    s = fmaf(z4[jj].x, ev.x, s); s = fmaf(z4[jj].y, ev.y, s);
                    s = fmaf(z4[jj].z, ev.z, s); s = fmaf(z4[jj].w, ev.w, s);
                }
#pragma unroll
                for (int off = 1; off < 16; off <<= 1) s += __shfl_xor(s, off, 64);
                const float d = fmaf(-2.0f, s, e2[col]);
                const unsigned long long key =
                    ((unsigned long long)fkey(d) << 32) | (unsigned)col;
                if (key < pk) pk = key;
            }
        }
    }
#pragma unroll
    for (int off = 16; off < 64; off <<= 1) {               // merge the 4 quads
        const unsigned long long o = __shfl_xor(pk, off, 64);
        if (o < pk) pk = o;
    }
    const int i = (int)(pk & 0xffffffffu);

    // Gather z_q, loss partial, index (plain stores, no atomics).
    const float4 qv = *(const float4*)(en + (size_t)i * DIM + lane * 4);
    const float4 zv = *(const float4*)(zq + (size_t)row * DIM + lane * 4);
    const float dx = qv.x - zv.x, dy = qv.y - zv.y, dz = qv.z - zv.z, dw = qv.w - zv.w;
    float s = dx * dx + dy * dy + dz * dz + dw * dw;
    *(float4*)(zq + (size_t)row * DIM + lane * 4) = qv;
#pragma unroll
    for (int off = 1; off < 64; off <<= 1) s += __shfl_xor(s, off, 64);
    if (lane == 0) {
        pl[row] = s;
        out_base[N_TOK * DIM + 1 + row] = (float)i;
    }
}

// ---------------------------------------------------------------------------
// K4: reduce 8192 per-row loss partials -> loss = 1.25 * sum / (8*1024*256).
// ---------------------------------------------------------------------------
__global__ __launch_bounds__(1024) void finalize_loss(const float* __restrict__ pl,
                                                      float* __restrict__ out) {
    __shared__ float sw[16];
    const int t = threadIdx.x;
    float s = 0.f;
#pragma unroll
    for (int j = 0; j < 8; j++) s += pl[t + j * 1024];
#pragma unroll
    for (int off = 1; off < 64; off <<= 1) s += __shfl_xor(s, off, 64);
    if ((t & 63) == 0) sw[t >> 6] = s;
    __syncthreads();
    if (t < 16) {
        float v = sw[t];
#pragma unroll
        for (int off = 1; off < 16; off <<= 1) v += __shfl_xor(v, off, 64);
        if (t == 0) out[N_TOK * DIM] = v * (1.25f / 2097152.0f);
    }
}

// ---------------------------------------------------------------------------
extern "C" void kernel_launch(void* const* d_in, const int* in_sizes, int n_in,
                              void* d_out, int out_size, void* d_ws, size_t ws_size,
                              hipStream_t stream) {
    const float* z   = (const float*)d_in[0];   // [8,1024,256] fp32
    const float* emb = (const float*)d_in[1];   // [8192,256] fp32
    float* out = (float*)d_out;                 // z_q[2097152] | loss[1] | idx[8192]
    char* ws = (char*)d_ws;

    // ws layout (byte offsets; total ~33.6 MB)
    float*          en    = (float*)(ws);                      //  8 MiB fp32 codes (normalized)
    unsigned short* esw   = (unsigned short*)(ws + 8388608);   //  4 MiB bf16 codes (frag-swizzled)
    unsigned short* zb    = (unsigned short*)(ws + 12582912);  //  4 MiB bf16 z (plain row-major)
    float*          e2    = (float*)(ws + 16777216);           // 32 KiB ||e||^2
    unsigned short* segMh = (unsigned short*)(ws + 16809984);  // 16 MiB fp16 [8192][1024]
    float*          pl    = (float*)(ws + 33587200);           // 32 KiB per-row loss partials

    // 1) normalize both inputs (emb -> en/esw/e2; z -> d_out z_q region + zb)
    l2norm_all<<<(N_E + N_TOK) / 4, 256, 0, stream>>>(z, emb, out, zb, en, esw, e2);
    // 2) bf16 MFMA approx distances (BK=64 dbuf, full code preload, 4 barriers)
    mfma_dist<<<64 * 64, 256, 0, stream>>>(zb, esw, e2, segMh);
    // 3) fused select + exact rescore + gather (wave per row, no atomics)
    select_rescore<<<N_TOK / 4, 256, 0, stream>>>(segMh, en, e2, out, out, pl);
    // 4) reduce loss partials
    finalize_loss<<<1, 1024, 0, stream>>>(pl, out);
}

// Round 4
// 141.505 us; speedup vs baseline: 1.5121x; 1.0851x over previous
//
#include <hip/hip_runtime.h>
#include <hip/hip_fp16.h>
#include <cfloat>
#include <math.h>

// Problem constants (fixed by the reference)
#define DIM    256
#define N_TOK  8192
#define N_E    8192
#define NSEG   1024         // 8-col groups per row
// Margin on d = ||e||^2 - 2*dot (bf16 approx pass, fp16-quantized group mins).
// Failure needs Dd(true)-Dd(approx-winner) + 2*quant > margin on a specific
// per-row pair: dot-err diff ~4.3sigma*6.8e-4 ~2.9e-3, fp16 quant 2*1e-3.
// 0.012 ~ 2.4x that. (Passed rounds 7-10; 0.016 and 0.008 also passed.)
#define MARGIN 0.012f

typedef __attribute__((ext_vector_type(8))) short bf16x8;
typedef __attribute__((ext_vector_type(4))) float f32x4;
typedef __attribute__((ext_vector_type(8))) unsigned short ushort8;

__device__ __forceinline__ unsigned short f2bf(float f) {      // RNE float->bf16
    unsigned u = __float_as_uint(f);
    unsigned r = u + 0x7fff + ((u >> 16) & 1);
    return (unsigned short)(r >> 16);
}
__device__ __forceinline__ unsigned fkey(float f) {            // monotone f32->u32
    unsigned u = __float_as_uint(f);
    return (u & 0x80000000u) ? ~u : (u | 0x80000000u);
}
__device__ __forceinline__ unsigned short f2h(float f) {       // RNE float->fp16 bits
    const __half h = __float2half(f);
    return *(const unsigned short*)&h;
}
__device__ __forceinline__ float h2f(unsigned short u) {
    __half_raw r; r.x = u;
    return __half2float((__half)r);
}

// ---------------------------------------------------------------------------
// K1: row-wise L2 normalize for BOTH inputs in one launch.
//  - z rows   -> zn fp32 (d_out scratch) + zb bf16 PLAIN row-major (the LDS
//    staging swizzle is applied via per-lane global addresses in mfma_dist).
//  - emb rows -> en fp32 + esw bf16 swizzled into exact MFMA A-fragment order
//    (frag16=row>>4, kc: 512 ushorts at (frag16*8+kc)*512; within:
//    ((k>>3&3)*16 + (row&15))*8 + (k&7)) + e2.
// ---------------------------------------------------------------------------
__global__ __launch_bounds__(256) void l2norm_all(const float* __restrict__ z,
                                                  const float* __restrict__ emb,
                                                  float* __restrict__ zn,
                                                  unsigned short* __restrict__ zb,
                                                  float* __restrict__ en,
                                                  unsigned short* __restrict__ esw,
                                                  float* __restrict__ e2) {
    const int lane = threadIdx.x & 63;
    const bool isE = blockIdx.x < (N_E / 4);
    const int row = (isE ? blockIdx.x : blockIdx.x - N_E / 4) * 4 + (threadIdx.x >> 6);
    const float* in = isE ? emb : z;
    float* out = isE ? en : zn;
    const float4 v = *(const float4*)(in + row * DIM + lane * 4);
    float s = v.x * v.x + v.y * v.y + v.z * v.z + v.w * v.w;
#pragma unroll
    for (int off = 1; off < 64; off <<= 1) s += __shfl_xor(s, off, 64);
    const float inv = 1.0f / fmaxf(sqrtf(s), 1e-12f);
    const float4 o = make_float4(v.x * inv, v.y * inv, v.z * inv, v.w * inv);
    *(float4*)(out + row * DIM + lane * 4) = o;
    ushort4 ob; ob.x = f2bf(o.x); ob.y = f2bf(o.y); ob.z = f2bf(o.z); ob.w = f2bf(o.w);
    const int k0 = lane * 4;
    if (isE) {
        const size_t sidx = ((size_t)((row >> 4) * 8 + (k0 >> 5)) * 64
                             + ((k0 >> 3) & 3) * 16 + (row & 15)) * 8 + (k0 & 7);
        *(ushort4*)(esw + sidx) = ob;
        float q = o.x * o.x + o.y * o.y + o.z * o.z + o.w * o.w;
#pragma unroll
        for (int off = 1; off < 64; off <<= 1) q += __shfl_xor(q, off, 64);
        if (lane == 0) e2[row] = q;
    } else {
        *(ushort4*)(zb + (size_t)row * DIM + k0) = ob;
    }
}

// ---------------------------------------------------------------------------
// K2: bf16 MFMA distance pass, v4 = v1 register structure + COUNTED-VMCNT
// barriers (T3/T4). 128x128 block tile, 4 waves of 64x64.
//  - z rows: As[2][128x8 chunks] BK=64 dbuf, XOR slot swizzle via per-lane
//    global addresses of global_load_lds; fragment ds_read at slot
//    (h*4+q)^(fr&7) -> 8 lanes/16B-slot, conflict-free (v1: 0 measured).
//  - codes: rolling register prefetch at distance THREE (v1 was 2; v3's full
//    preload spilled ~28 B/thread -> +30 MB HBM writes. 4 live groups = 64
//    regs, ~84 VGPR total, no spill).
//  - THE FIX: __syncthreads()'s implicit vmcnt(0) drained la prefetches
//    issued ~150-300 cyc earlier (L3 latency ~500) at every barrier. Replace
//    with asm s_waitcnt vmcnt(N) + raw s_barrier: N counted so only stage(p)
//    (issued a full iteration ago -> complete) is drained; younger la loads
//    STAY IN FLIGHT across the barrier. Queue (issue-order pinned by
//    sched_barrier(0) after each stage): B0=12, B1=B2=8, B3=4.
//    Race-free: each wave's lgkm waits retire its As reads before it can
//    reach the next barrier; sched_barrier(0) after s_barrier stops ds_read
//    hoisting; "memory" clobber stops loads crossing the waitcnt.
//  - epilogue: wave-private smw pad, zero barriers; NT segMh store; e2q
//    issued at top of p=3 (all correctness-validated in rounds 1/3).
// Numerics identical to v1 (same MFMA order/operands) -> MARGIN unchanged.
// ---------------------------------------------------------------------------
__global__ __launch_bounds__(256, 2) void mfma_dist(const unsigned short* __restrict__ zb,
                                                    const unsigned short* __restrict__ esw,
                                                    const float* __restrict__ e2,
                                                    unsigned short* __restrict__ segMh) {
    __shared__ __align__(16) unsigned short As[2][128 * 64];   // 2 x 16 KB z chunk-pair
    __shared__ float smw[4][8][64];                            // 8 KB per-wave pads

    const int tid  = threadIdx.x;
    const int lane = tid & 63;
    const int wave = tid >> 6;
    const int wm = wave & 1, wn = wave >> 1;
    const int row0 = (blockIdx.x & 63) * 128;
    const int col0 = (blockIdx.x >> 6) * 128;
    const int fr = lane & 15, q = lane >> 4;

    f32x4 acc[4][4];
#pragma unroll
    for (int ci = 0; ci < 4; ci++)
#pragma unroll
        for (int zi = 0; zi < 4; zi++) acc[ci][zi] = (f32x4){0.f, 0.f, 0.f, 0.f};

    // Code fragments: frag16 group aBase+i, address = frag*4096 + kc*512 + lane*8
    const int aBase = (col0 >> 4) + wn * 4;
    auto la = [&](int i, int kc) {
        return *(const bf16x8*)(esw + (size_t)(aBase + i) * 4096 + kc * 512 + lane * 8);
    };
    // z staging, pair p (k in [p*64, p*64+64)): wave stages rows wave*32..+31,
    // 4 instrs of 1 KB; lane -> row (lane>>3) of the 8-row slab, slot lane&7.
    // Global chunk fetched = p*8 + (slot ^ (r&7)); r&7 == (lane>>3)&7 here.
    const int cxor = (lane & 7) ^ ((lane >> 3) & 7);            // const per lane
    const unsigned short* gZ = zb + (size_t)(row0 + wave * 32 + (lane >> 3)) * DIM + cxor * 8;
    auto stage = [&](int buf, int p) {
#pragma unroll
        for (int j = 0; j < 4; j++) {
            __builtin_amdgcn_global_load_lds(
                (const __attribute__((address_space(1))) unsigned int*)(gZ + (size_t)j * 8 * DIM + p * 64),
                (__attribute__((address_space(3))) unsigned int*)&As[buf][(wave * 32 + j * 8) * 64],
                16, 0, 0);
        }
    };
    // z fragment from LDS: kc = 2p+h, logical chunk h*4+q, slot ^= (fr&7).
    auto lz = [&](int buf, int i, int h) {
        const int r = wm * 64 + i * 16 + fr;
        const int slot = (h * 4 + q) ^ (fr & 7);
        return *(const bf16x8*)&As[buf][r * 64 + slot * 8];
    };

    // Prologue: stage(0) FIRST (oldest in vm queue), then ca kc 0..2.
    bf16x8 ca[8][4];
    stage(0, 0);
    __builtin_amdgcn_sched_barrier(0);       // pin: S0 precedes A0..A2 in queue
#pragma unroll
    for (int kc = 0; kc < 3; kc++)
#pragma unroll
        for (int i = 0; i < 4; i++) ca[kc][i] = la(i, kc);

    float4 e2q[4];

#pragma unroll
    for (int p = 0; p < 4; p++) {
        // Counted drain: stage(p) done; newer la prefetches stay in flight.
        if (p == 0)      asm volatile("s_waitcnt vmcnt(12)" ::: "memory");
        else if (p == 3) asm volatile("s_waitcnt vmcnt(4)"  ::: "memory");
        else             asm volatile("s_waitcnt vmcnt(8)"  ::: "memory");
        __builtin_amdgcn_s_barrier();
        __builtin_amdgcn_sched_barrier(0);   // nothing crosses the barrier
        if (p < 3) {
            stage((p + 1) & 1, p + 1);
            __builtin_amdgcn_sched_barrier(0);  // pin: S(p+1) precedes this iter's la
        }
        if (p == 3) {                        // epilogue data, ~600 cyc before use
#pragma unroll
            for (int ci = 0; ci < 4; ci++)
                e2q[ci] = *(const float4*)&e2[col0 + wn * 64 + ci * 16 + q * 4];
        }
#pragma unroll
        for (int h = 0; h < 2; h++) {
            const int kc = 2 * p + h;
            if (kc + 3 < 8) {                // rolling refill, distance 3
#pragma unroll
                for (int i = 0; i < 4; i++) ca[kc + 3][i] = la(i, kc + 3);
            }
            bf16x8 zfr[4];
#pragma unroll
            for (int i = 0; i < 4; i++) zfr[i] = lz(p & 1, i, h);
#pragma unroll
            for (int ci = 0; ci < 4; ci++)
#pragma unroll
                for (int zi = 0; zi < 4; zi++)
                    acc[ci][zi] = __builtin_amdgcn_mfma_f32_16x16x32_bf16(ca[kc][ci], zfr[zi], acc[ci][zi], 0, 0, 0);
        }
    }

    // Per-wave epilogue, NO barriers. C/D: m (code) = (lane>>4)*4 + reg,
    // n (z row) = lane&15. Cross-lane handoff stays inside the wave.
#pragma unroll
    for (int ci = 0; ci < 4; ci++) {
#pragma unroll
        for (int zi = 0; zi < 4; zi++) {
            const float t0 = fmaf(-2.0f, acc[ci][zi][0], e2q[ci].x);
            const float t1 = fmaf(-2.0f, acc[ci][zi][1], e2q[ci].y);
            const float t2 = fmaf(-2.0f, acc[ci][zi][2], e2q[ci].z);
            const float t3 = fmaf(-2.0f, acc[ci][zi][3], e2q[ci].w);
            float mm = fminf(fminf(t0, t1), fminf(t2, t3));   // min over 4 codes (regs)
            mm = fminf(mm, __shfl_xor(mm, 16, 64));           // pair quads: 8-code min
            // q==0 holds codes 0..7 min; q==2 holds codes 8..15 min
            if (q == 0) smw[wave][ci * 2 + 0][zi * 16 + fr] = mm;
            if (q == 2) smw[wave][ci * 2 + 1][zi * 16 + fr] = mm;
        }
    }
    // Transpose out of the wave-private pad: lane = local row, 8 segs packed.
    // Nontemporal: 16 MB result stream must not evict esw/zb from L2.
    ushort8 o8;
#pragma unroll
    for (int j = 0; j < 8; j++) o8[j] = f2h(smw[wave][j][lane]);
    __builtin_nontemporal_store(
        o8, (ushort8*)&segMh[(size_t)(row0 + wm * 64 + lane) * NSEG + (col0 >> 3) + wn * 8]);
}

// ---------------------------------------------------------------------------
// K3 (fused select+rescore+gather): one WAVE per row, ZERO atomics.
//  1. read 1024 fp16 group-mins (2 KB contiguous, nontemporal), shuffle-min
//  2. ballot-flag 8-col groups within m+MARGIN (winner always self-flags)
//  3. wave-uniform bit-walk; exact fp32 rescore (16 lanes split the 256-dim
//     dot, 4 cols per pass, 2 passes/group); packed (key|col) running min
//     -> exact argmin with lowest-index tie-break (matches jnp.argmin)
//  4. gather en[idx] -> z_q, per-row loss partial to pl[row], index out.
// ---------------------------------------------------------------------------
__global__ __launch_bounds__(256) void select_rescore(const unsigned short* __restrict__ segMh,
                                                      const float* __restrict__ en,
                                                      const float* __restrict__ e2,
                                                      float* zq,        // d_out: z_norm in / z_q out
                                                      float* out_base,  // d_out
                                                      float* __restrict__ pl) {
    const int lane = threadIdx.x & 63;
    const int row  = (blockIdx.x << 2) + (threadIdx.x >> 6);
    const unsigned short* ph = segMh + (size_t)row * NSEG + lane * 16;
    const ushort8 u0 = __builtin_nontemporal_load((const ushort8*)ph);
    const ushort8 u1 = __builtin_nontemporal_load((const ushort8*)(ph + 8));
    float vv[16];
#pragma unroll
    for (int j = 0; j < 8; j++) { vv[j] = h2f(u0[j]); vv[8 + j] = h2f(u1[j]); }
    float m = vv[0];
#pragma unroll
    for (int j = 1; j < 16; j++) m = fminf(m, vv[j]);
#pragma unroll
    for (int off = 1; off < 64; off <<= 1) m = fminf(m, __shfl_xor(m, off, 64));
    const float thr = m + MARGIN;

    // z row in 16-lane-split layout for the rescore dots (shared by all groups)
    const int q = lane >> 4, f = lane & 15;
    const float4* zp = (const float4*)(zq + (size_t)row * DIM);
    float4 z4[4];
#pragma unroll
    for (int j = 0; j < 4; j++) z4[j] = zp[j * 16 + f];

    unsigned long long pk = ~0ull;
#pragma unroll
    for (int j = 0; j < 16; j++) {
        unsigned long long bal = __ballot(vv[j] <= thr);   // wave-uniform
        while (bal) {
            const int l = __ffsll(bal) - 1;
            bal &= bal - 1;
            const int seg = l * 16 + j;                    // lane l holds segs l*16+j
#pragma unroll
            for (int g = 0; g < 2; g++) {
                const int col = seg * 8 + g * 4 + q;
                const float4* ep = (const float4*)(en + (size_t)col * DIM);
                float s = 0.f;
#pragma unroll
                for (int jj = 0; jj < 4; jj++) {
                    const float4 ev = ep[jj * 16 + f];
                    s = fmaf(z4[jj].x, ev.x, s); s = fmaf(z4[jj].y, ev.y, s);
                    s = fmaf(z4[jj].z, ev.z, s); s = fmaf(z4[jj].w, ev.w, s);
                }
#pragma unroll
                for (int off = 1; off < 16; off <<= 1) s += __shfl_xor(s, off, 64);
                const float d = fmaf(-2.0f, s, e2[col]);
                const unsigned long long key =
                    ((unsigned long long)fkey(d) << 32) | (unsigned)col;
                if (key < pk) pk = key;
            }
        }
    }
#pragma unroll
    for (int off = 16; off < 64; off <<= 1) {               // merge the 4 quads
        const unsigned long long o = __shfl_xor(pk, off, 64);
        if (o < pk) pk = o;
    }
    const int i = (int)(pk & 0xffffffffu);

    // Gather z_q, loss partial, index (plain stores, no atomics).
    const float4 qv = *(const float4*)(en + (size_t)i * DIM + lane * 4);
    const float4 zv = *(const float4*)(zq + (size_t)row * DIM + lane * 4);
    const float dx = qv.x - zv.x, dy = qv.y - zv.y, dz = qv.z - zv.z, dw = qv.w - zv.w;
    float s = dx * dx + dy * dy + dz * dz + dw * dw;
    *(float4*)(zq + (size_t)row * DIM + lane * 4) = qv;
#pragma unroll
    for (int off = 1; off < 64; off <<= 1) s += __shfl_xor(s, off, 64);
    if (lane == 0) {
        pl[row] = s;
        out_base[N_TOK * DIM + 1 + row] = (float)i;
    }
}

// ---------------------------------------------------------------------------
// K4: reduce 8192 per-row loss partials -> loss = 1.25 * sum / (8*1024*256).
// ---------------------------------------------------------------------------
__global__ __launch_bounds__(1024) void finalize_loss(const float* __restrict__ pl,
                                                      float* __restrict__ out) {
    __shared__ float sw[16];
    const int t = threadIdx.x;
    float s = 0.f;
#pragma unroll
    for (int j = 0; j < 8; j++) s += pl[t + j * 1024];
#pragma unroll
    for (int off = 1; off < 64; off <<= 1) s += __shfl_xor(s, off, 64);
    if ((t & 63) == 0) sw[t >> 6] = s;
    __syncthreads();
    if (t < 16) {
        float v = sw[t];
#pragma unroll
        for (int off = 1; off < 16; off <<= 1) v += __shfl_xor(v, off, 64);
        if (t == 0) out[N_TOK * DIM] = v * (1.25f / 2097152.0f);
    }
}

// ---------------------------------------------------------------------------
extern "C" void kernel_launch(void* const* d_in, const int* in_sizes, int n_in,
                              void* d_out, int out_size, void* d_ws, size_t ws_size,
                              hipStream_t stream) {
    const float* z   = (const float*)d_in[0];   // [8,1024,256] fp32
    const float* emb = (const float*)d_in[1];   // [8192,256] fp32
    float* out = (float*)d_out;                 // z_q[2097152] | loss[1] | idx[8192]
    char* ws = (char*)d_ws;

    // ws layout (byte offsets; total ~33.6 MB)
    float*          en    = (float*)(ws);                      //  8 MiB fp32 codes (normalized)
    unsigned short* esw   = (unsigned short*)(ws + 8388608);   //  4 MiB bf16 codes (frag-swizzled)
    unsigned short* zb    = (unsigned short*)(ws + 12582912);  //  4 MiB bf16 z (plain row-major)
    float*          e2    = (float*)(ws + 16777216);           // 32 KiB ||e||^2
    unsigned short* segMh = (unsigned short*)(ws + 16809984);  // 16 MiB fp16 [8192][1024]
    float*          pl    = (float*)(ws + 33587200);           // 32 KiB per-row loss partials

    // 1) normalize both inputs (emb -> en/esw/e2; z -> d_out z_q region + zb)
    l2norm_all<<<(N_E + N_TOK) / 4, 256, 0, stream>>>(z, emb, out, zb, en, esw, e2);
    // 2) bf16 MFMA approx distances (BK=64 dbuf, counted-vmcnt barriers)
    mfma_dist<<<64 * 64, 256, 0, stream>>>(zb, esw, e2, segMh);
    // 3) fused select + exact rescore + gather (wave per row, no atomics)
    select_rescore<<<N_TOK / 4, 256, 0, stream>>>(segMh, en, e2, out, out, pl);
    // 4) reduce loss partials
    finalize_loss<<<1, 1024, 0, stream>>>(pl, out);
}

// Round 5
// 137.403 us; speedup vs baseline: 1.5573x; 1.0299x over previous
//
#include <hip/hip_runtime.h>
#include <hip/hip_fp16.h>
#include <cfloat>
#include <math.h>

// Problem constants (fixed by the reference)
#define DIM    256
#define N_TOK  8192
#define N_E    8192
#define NSEG   1024         // 8-col groups per row
// Margin on d = ||e||^2 - 2*dot (bf16 approx pass, fp16-quantized group mins).
// K2 uses e2 == 1.0f (codes are unit-norm after l2norm; true e2 = 1 +- 2e-7,
// absorbed by the margin). K3 rescores with the true fp32 e2.
#define MARGIN 0.012f

typedef __attribute__((ext_vector_type(8))) short bf16x8;
typedef __attribute__((ext_vector_type(4))) float f32x4;
typedef __attribute__((ext_vector_type(8))) unsigned short ushort8;

__device__ __forceinline__ unsigned short f2bf(float f) {      // RNE float->bf16
    unsigned u = __float_as_uint(f);
    unsigned r = u + 0x7fff + ((u >> 16) & 1);
    return (unsigned short)(r >> 16);
}
__device__ __forceinline__ unsigned fkey(float f) {            // monotone f32->u32
    unsigned u = __float_as_uint(f);
    return (u & 0x80000000u) ? ~u : (u | 0x80000000u);
}
__device__ __forceinline__ unsigned short f2h(float f) {       // RNE float->fp16 bits
    const __half h = __float2half(f);
    return *(const unsigned short*)&h;
}
__device__ __forceinline__ float h2f(unsigned short u) {
    __half_raw r; r.x = u;
    return __half2float((__half)r);
}

// ---------------------------------------------------------------------------
// K1: row-wise L2 normalize for BOTH inputs in one launch.
//  - z rows   -> zn fp32 (d_out scratch) + zb bf16 PLAIN row-major (the LDS
//    staging swizzle is applied via per-lane global addresses in mfma_dist).
//  - emb rows -> en fp32 + esw bf16 swizzled into exact MFMA A-fragment order
//    (frag16=row>>4, kc: 512 ushorts at (frag16*8+kc)*512; within:
//    ((k>>3&3)*16 + (row&15))*8 + (k&7)) + e2.
// ---------------------------------------------------------------------------
__global__ __launch_bounds__(256) void l2norm_all(const float* __restrict__ z,
                                                  const float* __restrict__ emb,
                                                  float* __restrict__ zn,
                                                  unsigned short* __restrict__ zb,
                                                  float* __restrict__ en,
                                                  unsigned short* __restrict__ esw,
                                                  float* __restrict__ e2) {
    const int lane = threadIdx.x & 63;
    const bool isE = blockIdx.x < (N_E / 4);
    const int row = (isE ? blockIdx.x : blockIdx.x - N_E / 4) * 4 + (threadIdx.x >> 6);
    const float* in = isE ? emb : z;
    float* out = isE ? en : zn;
    const float4 v = *(const float4*)(in + row * DIM + lane * 4);
    float s = v.x * v.x + v.y * v.y + v.z * v.z + v.w * v.w;
#pragma unroll
    for (int off = 1; off < 64; off <<= 1) s += __shfl_xor(s, off, 64);
    const float inv = 1.0f / fmaxf(sqrtf(s), 1e-12f);
    const float4 o = make_float4(v.x * inv, v.y * inv, v.z * inv, v.w * inv);
    *(float4*)(out + row * DIM + lane * 4) = o;
    ushort4 ob; ob.x = f2bf(o.x); ob.y = f2bf(o.y); ob.z = f2bf(o.z); ob.w = f2bf(o.w);
    const int k0 = lane * 4;
    if (isE) {
        const size_t sidx = ((size_t)((row >> 4) * 8 + (k0 >> 5)) * 64
                             + ((k0 >> 3) & 3) * 16 + (row & 15)) * 8 + (k0 & 7);
        *(ushort4*)(esw + sidx) = ob;
        float q = o.x * o.x + o.y * o.y + o.z * o.z + o.w * o.w;
#pragma unroll
        for (int off = 1; off < 64; off <<= 1) q += __shfl_xor(q, off, 64);
        if (lane == 0) e2[row] = q;
    } else {
        *(ushort4*)(zb + (size_t)row * DIM + k0) = ob;
    }
}

// ---------------------------------------------------------------------------
// K2: bf16 MFMA distance pass, v5 = v1 structure tuned for OCCUPANCY.
// 128x128 block tile, 4 waves of 64x64. v4 post-mortem: counted-vmcnt ==
// full-drain (both ~50us) -> NOT schedule-bound; Occupancy 27% (2 waves/SIMD,
// wave MFMA-duty ~17%) -> latency/occupancy-bound. v5 targets 3 blocks/CU:
//  - LDS 40->32 KB: epilogue pad ALIASED into As[0] (after the p=3 barrier
//    no stage writes remain and phase-3 reads only As[1]; pads wave-private
//    -> still zero epilogue barriers).
//  - regs ~158/wave: ca window distance-2 (3 live groups, uniform vmcnt(8)
//    at every barrier: queue is always [S(p), A, A]), e2 DROPPED from K2
//    (codes unit-norm: e2 = 1 +- 2e-7 << fp16 quant; epilogue uses constant
//    1.0f; K3 keeps exact e2). launch_bounds(256,3) caps at 170 -> no spill.
//  - segMh store reverted to REGULAR (v3/v4's nontemporal hint caused ~3x
//    write amplification: WRITE_SIZE 16.4 -> 50 MB at 64B line granularity).
// Numerics: same MFMA order/operands as v1; segMh differs only by the
// |e2-1| <= 2e-7 epilogue constant (<< MARGIN slack).
// ---------------------------------------------------------------------------
__global__ __launch_bounds__(256, 3) void mfma_dist(const unsigned short* __restrict__ zb,
                                                    const unsigned short* __restrict__ esw,
                                                    unsigned short* __restrict__ segMh) {
    __shared__ __align__(16) unsigned short As[2][128 * 64];   // 2 x 16 KB z chunk-pair
    float* sm = reinterpret_cast<float*>(As);                  // epilogue pads alias As[0]

    const int tid  = threadIdx.x;
    const int lane = tid & 63;
    const int wave = tid >> 6;
    const int wm = wave & 1, wn = wave >> 1;
    const int row0 = (blockIdx.x & 63) * 128;
    const int col0 = (blockIdx.x >> 6) * 128;
    const int fr = lane & 15, q = lane >> 4;

    f32x4 acc[4][4];
#pragma unroll
    for (int ci = 0; ci < 4; ci++)
#pragma unroll
        for (int zi = 0; zi < 4; zi++) acc[ci][zi] = (f32x4){0.f, 0.f, 0.f, 0.f};

    // Code fragments: frag16 group aBase+i, address = frag*4096 + kc*512 + lane*8
    const int aBase = (col0 >> 4) + wn * 4;
    auto la = [&](int i, int kc) {
        return *(const bf16x8*)(esw + (size_t)(aBase + i) * 4096 + kc * 512 + lane * 8);
    };
    // z staging, pair p (k in [p*64, p*64+64)): wave stages rows wave*32..+31,
    // 4 instrs of 1 KB; lane -> row (lane>>3) of the 8-row slab, slot lane&7.
    // Global chunk fetched = p*8 + (slot ^ (r&7)); r&7 == (lane>>3)&7 here.
    const int cxor = (lane & 7) ^ ((lane >> 3) & 7);            // const per lane
    const unsigned short* gZ = zb + (size_t)(row0 + wave * 32 + (lane >> 3)) * DIM + cxor * 8;
    auto stage = [&](int buf, int p) {
#pragma unroll
        for (int j = 0; j < 4; j++) {
            __builtin_amdgcn_global_load_lds(
                (const __attribute__((address_space(1))) unsigned int*)(gZ + (size_t)j * 8 * DIM + p * 64),
                (__attribute__((address_space(3))) unsigned int*)&As[buf][(wave * 32 + j * 8) * 64],
                16, 0, 0);
        }
    };
    // z fragment from LDS: kc = 2p+h, logical chunk h*4+q, slot ^= (fr&7).
    auto lz = [&](int buf, int i, int h) {
        const int r = wm * 64 + i * 16 + fr;
        const int slot = (h * 4 + q) ^ (fr & 7);
        return *(const bf16x8*)&As[buf][r * 64 + slot * 8];
    };

    // Prologue: stage(0) first (oldest in vm queue), then ca kc 0,1.
    bf16x8 ca[8][4];
    stage(0, 0);
    __builtin_amdgcn_sched_barrier(0);       // pin: S0 precedes A0,A1 in queue
#pragma unroll
    for (int kc = 0; kc < 2; kc++)
#pragma unroll
        for (int i = 0; i < 4; i++) ca[kc][i] = la(i, kc);

#pragma unroll
    for (int p = 0; p < 4; p++) {
        // Queue at every barrier: [S(p), A, A] -> vmcnt(8) drains S(p) only;
        // the 2 la prefetch groups stay in flight across the barrier.
        asm volatile("s_waitcnt vmcnt(8)" ::: "memory");
        __builtin_amdgcn_s_barrier();
        __builtin_amdgcn_sched_barrier(0);   // nothing crosses the barrier
        if (p < 3) {
            stage((p + 1) & 1, p + 1);
            __builtin_amdgcn_sched_barrier(0);  // pin: S(p+1) precedes this iter's la
        }
#pragma unroll
        for (int h = 0; h < 2; h++) {
            const int kc = 2 * p + h;
            if (kc + 2 < 8) {                // rolling refill, distance 2
#pragma unroll
                for (int i = 0; i < 4; i++) ca[kc + 2][i] = la(i, kc + 2);
            }
            bf16x8 zfr[4];
#pragma unroll
            for (int i = 0; i < 4; i++) zfr[i] = lz(p & 1, i, h);
#pragma unroll
            for (int ci = 0; ci < 4; ci++)
#pragma unroll
                for (int zi = 0; zi < 4; zi++)
                    acc[ci][zi] = __builtin_amdgcn_mfma_f32_16x16x32_bf16(ca[kc][ci], zfr[zi], acc[ci][zi], 0, 0, 0);
        }
    }

    // Per-wave epilogue, NO barriers. C/D: m (code) = (lane>>4)*4 + reg,
    // n (z row) = lane&15. d = 1.0 - 2*dot (codes unit-norm). Pad aliases
    // As[0] (wave-private 2 KB slab) - safe post-p3-barrier, see header.
#pragma unroll
    for (int ci = 0; ci < 4; ci++) {
#pragma unroll
        for (int zi = 0; zi < 4; zi++) {
            const float t0 = fmaf(-2.0f, acc[ci][zi][0], 1.0f);
            const float t1 = fmaf(-2.0f, acc[ci][zi][1], 1.0f);
            const float t2 = fmaf(-2.0f, acc[ci][zi][2], 1.0f);
            const float t3 = fmaf(-2.0f, acc[ci][zi][3], 1.0f);
            float mm = fminf(fminf(t0, t1), fminf(t2, t3));   // min over 4 codes (regs)
            mm = fminf(mm, __shfl_xor(mm, 16, 64));           // pair quads: 8-code min
            // q==0 holds codes 0..7 min; q==2 holds codes 8..15 min
            if (q == 0) sm[wave * 512 + (ci * 2 + 0) * 64 + zi * 16 + fr] = mm;
            if (q == 2) sm[wave * 512 + (ci * 2 + 1) * 64 + zi * 16 + fr] = mm;
        }
    }
    // Transpose out of the wave-private pad: lane = local row, 8 segs packed.
    ushort8 o8;
#pragma unroll
    for (int j = 0; j < 8; j++) o8[j] = f2h(sm[wave * 512 + j * 64 + lane]);
    *(ushort8*)&segMh[(size_t)(row0 + wm * 64 + lane) * NSEG + (col0 >> 3) + wn * 8] = o8;
}

// ---------------------------------------------------------------------------
// K3 (fused select+rescore+gather): one WAVE per row, ZERO atomics.
//  1. read 1024 fp16 group-mins (2 KB contiguous), shuffle-min -> threshold
//  2. ballot-flag 8-col groups within m+MARGIN (winner always self-flags)
//  3. wave-uniform bit-walk, TWO groups per iteration (16 float4 gathers in
//     flight -> halves the serial L2/L3-latency chain); exact fp32 rescore
//     (16 lanes split the 256-dim dot, 4 cols per pass); packed (key|col)
//     running min -> exact argmin, lowest-index tie-break (jnp.argmin);
//     min-reduction is order-independent so dual-issue preserves semantics.
//  4. gather en[idx] -> z_q, per-row loss partial to pl[row], index out.
// ---------------------------------------------------------------------------
__global__ __launch_bounds__(256) void select_rescore(const unsigned short* __restrict__ segMh,
                                                      const float* __restrict__ en,
                                                      const float* __restrict__ e2,
                                                      float* zq,        // d_out: z_norm in / z_q out
                                                      float* out_base,  // d_out
                                                      float* __restrict__ pl) {
    const int lane = threadIdx.x & 63;
    const int row  = (blockIdx.x << 2) + (threadIdx.x >> 6);
    const unsigned short* ph = segMh + (size_t)row * NSEG + lane * 16;
    const ushort8 u0 = *(const ushort8*)ph;
    const ushort8 u1 = *(const ushort8*)(ph + 8);
    float vv[16];
#pragma unroll
    for (int j = 0; j < 8; j++) { vv[j] = h2f(u0[j]); vv[8 + j] = h2f(u1[j]); }
    float m = vv[0];
#pragma unroll
    for (int j = 1; j < 16; j++) m = fminf(m, vv[j]);
#pragma unroll
    for (int off = 1; off < 64; off <<= 1) m = fminf(m, __shfl_xor(m, off, 64));
    const float thr = m + MARGIN;

    // z row in 16-lane-split layout for the rescore dots (shared by all groups)
    const int q = lane >> 4, f = lane & 15;
    const float4* zp = (const float4*)(zq + (size_t)row * DIM);
    float4 z4[4];
#pragma unroll
    for (int j = 0; j < 4; j++) z4[j] = zp[j * 16 + f];

    unsigned long long pk = ~0ull;
#pragma unroll
    for (int j = 0; j < 16; j++) {
        unsigned long long bal = __ballot(vv[j] <= thr);   // wave-uniform
        while (bal) {
            const int l1 = __ffsll(bal) - 1; bal &= bal - 1;
            int l2 = l1;
            if (bal) { l2 = __ffsll(bal) - 1; bal &= bal - 1; }  // dup if odd (harmless)
            const int segA = l1 * 16 + j, segB = l2 * 16 + j;
            const int cA0 = segA * 8 + q,     cA1 = segA * 8 + 4 + q;
            const int cB0 = segB * 8 + q,     cB1 = segB * 8 + 4 + q;
            const float4* pA0 = (const float4*)(en + (size_t)cA0 * DIM);
            const float4* pA1 = (const float4*)(en + (size_t)cA1 * DIM);
            const float4* pB0 = (const float4*)(en + (size_t)cB0 * DIM);
            const float4* pB1 = (const float4*)(en + (size_t)cB1 * DIM);
            float4 eA0[4], eA1[4], eB0[4], eB1[4];
#pragma unroll
            for (int jj = 0; jj < 4; jj++) {              // 16 loads in flight
                eA0[jj] = pA0[jj * 16 + f]; eA1[jj] = pA1[jj * 16 + f];
                eB0[jj] = pB0[jj * 16 + f]; eB1[jj] = pB1[jj * 16 + f];
            }
            float sA0 = 0.f, sA1 = 0.f, sB0 = 0.f, sB1 = 0.f;
#pragma unroll
            for (int jj = 0; jj < 4; jj++) {
                sA0 = fmaf(z4[jj].x, eA0[jj].x, sA0); sA0 = fmaf(z4[jj].y, eA0[jj].y, sA0);
                sA0 = fmaf(z4[jj].z, eA0[jj].z, sA0); sA0 = fmaf(z4[jj].w, eA0[jj].w, sA0);
                sA1 = fmaf(z4[jj].x, eA1[jj].x, sA1); sA1 = fmaf(z4[jj].y, eA1[jj].y, sA1);
                sA1 = fmaf(z4[jj].z, eA1[jj].z, sA1); sA1 = fmaf(z4[jj].w, eA1[jj].w, sA1);
                sB0 = fmaf(z4[jj].x, eB0[jj].x, sB0); sB0 = fmaf(z4[jj].y, eB0[jj].y, sB0);
                sB0 = fmaf(z4[jj].z, eB0[jj].z, sB0); sB0 = fmaf(z4[jj].w, eB0[jj].w, sB0);
                sB1 = fmaf(z4[jj].x, eB1[jj].x, sB1); sB1 = fmaf(z4[jj].y, eB1[jj].y, sB1);
                sB1 = fmaf(z4[jj].z, eB1[jj].z, sB1); sB1 = fmaf(z4[jj].w, eB1[jj].w, sB1);
            }
#pragma unroll
            for (int off = 1; off < 16; off <<= 1) {
                sA0 += __shfl_xor(sA0, off, 64); sA1 += __shfl_xor(sA1, off, 64);
                sB0 += __shfl_xor(sB0, off, 64); sB1 += __shfl_xor(sB1, off, 64);
            }
            const float dA0 = fmaf(-2.0f, sA0, e2[cA0]);
            const float dA1 = fmaf(-2.0f, sA1, e2[cA1]);
            const float dB0 = fmaf(-2.0f, sB0, e2[cB0]);
            const float dB1 = fmaf(-2.0f, sB1, e2[cB1]);
            unsigned long long k;
            k = ((unsigned long long)fkey(dA0) << 32) | (unsigned)cA0; if (k < pk) pk = k;
            k = ((unsigned long long)fkey(dA1) << 32) | (unsigned)cA1; if (k < pk) pk = k;
            k = ((unsigned long long)fkey(dB0) << 32) | (unsigned)cB0; if (k < pk) pk = k;
            k = ((unsigned long long)fkey(dB1) << 32) | (unsigned)cB1; if (k < pk) pk = k;
        }
    }
#pragma unroll
    for (int off = 16; off < 64; off <<= 1) {               // merge the 4 quads
        const unsigned long long o = __shfl_xor(pk, off, 64);
        if (o < pk) pk = o;
    }
    const int i = (int)(pk & 0xffffffffu);

    // Gather z_q, loss partial, index (plain stores, no atomics).
    const float4 qv = *(const float4*)(en + (size_t)i * DIM + lane * 4);
    const float4 zv = *(const float4*)(zq + (size_t)row * DIM + lane * 4);
    const float dx = qv.x - zv.x, dy = qv.y - zv.y, dz = qv.z - zv.z, dw = qv.w - zv.w;
    float s = dx * dx + dy * dy + dz * dz + dw * dw;
    *(float4*)(zq + (size_t)row * DIM + lane * 4) = qv;
#pragma unroll
    for (int off = 1; off < 64; off <<= 1) s += __shfl_xor(s, off, 64);
    if (lane == 0) {
        pl[row] = s;
        out_base[N_TOK * DIM + 1 + row] = (float)i;
    }
}

// ---------------------------------------------------------------------------
// K4: reduce 8192 per-row loss partials -> loss = 1.25 * sum / (8*1024*256).
// ---------------------------------------------------------------------------
__global__ __launch_bounds__(1024) void finalize_loss(const float* __restrict__ pl,
                                                      float* __restrict__ out) {
    __shared__ float sw[16];
    const int t = threadIdx.x;
    float s = 0.f;
#pragma unroll
    for (int j = 0; j < 8; j++) s += pl[t + j * 1024];
#pragma unroll
    for (int off = 1; off < 64; off <<= 1) s += __shfl_xor(s, off, 64);
    if ((t & 63) == 0) sw[t >> 6] = s;
    __syncthreads();
    if (t < 16) {
        float v = sw[t];
#pragma unroll
        for (int off = 1; off < 16; off <<= 1) v += __shfl_xor(v, off, 64);
        if (t == 0) out[N_TOK * DIM] = v * (1.25f / 2097152.0f);
    }
}

// ---------------------------------------------------------------------------
extern "C" void kernel_launch(void* const* d_in, const int* in_sizes, int n_in,
                              void* d_out, int out_size, void* d_ws, size_t ws_size,
                              hipStream_t stream) {
    const float* z   = (const float*)d_in[0];   // [8,1024,256] fp32
    const float* emb = (const float*)d_in[1];   // [8192,256] fp32
    float* out = (float*)d_out;                 // z_q[2097152] | loss[1] | idx[8192]
    char* ws = (char*)d_ws;

    // ws layout (byte offsets; total ~33.6 MB)
    float*          en    = (float*)(ws);                      //  8 MiB fp32 codes (normalized)
    unsigned short* esw   = (unsigned short*)(ws + 8388608);   //  4 MiB bf16 codes (frag-swizzled)
    unsigned short* zb    = (unsigned short*)(ws + 12582912);  //  4 MiB bf16 z (plain row-major)
    float*          e2    = (float*)(ws + 16777216);           // 32 KiB ||e||^2
    unsigned short* segMh = (unsigned short*)(ws + 16809984);  // 16 MiB fp16 [8192][1024]
    float*          pl    = (float*)(ws + 33587200);           // 32 KiB per-row loss partials

    // 1) normalize both inputs (emb -> en/esw/e2; z -> d_out z_q region + zb)
    l2norm_all<<<(N_E + N_TOK) / 4, 256, 0, stream>>>(z, emb, out, zb, en, esw, e2);
    // 2) bf16 MFMA approx distances (32 KB LDS, 3 blocks/CU target)
    mfma_dist<<<64 * 64, 256, 0, stream>>>(zb, esw, segMh);
    // 3) fused select + exact rescore + gather (wave per row, dual-group walk)
    select_rescore<<<N_TOK / 4, 256, 0, stream>>>(segMh, en, e2, out, out, pl);
    // 4) reduce loss partials
    finalize_loss<<<1, 1024, 0, stream>>>(pl, out);
}

// Round 7
// 128.761 us; speedup vs baseline: 1.6618x; 1.0671x over previous
//
#include <hip/hip_runtime.h>
#include <hip/hip_fp16.h>
#include <cfloat>
#include <math.h>

// Problem constants (fixed by the reference)
#define DIM    256
#define N_TOK  8192
#define N_E    8192
#define NSEG   1024         // 8-col groups per row
// Margin on d = ||e||^2 - 2*dot (bf16 approx pass, fp16-quantized group mins).
// K2 uses e2 == 1.0f (codes are unit-norm after l2norm; true e2 = 1 +- 2e-7,
// absorbed by the margin). K3 rescores with the true fp32 e2.
#define MARGIN 0.012f

typedef __attribute__((ext_vector_type(8))) short bf16x8;
typedef __attribute__((ext_vector_type(4))) float f32x4;
typedef __attribute__((ext_vector_type(8))) unsigned short ushort8;

__device__ __forceinline__ unsigned short f2bf(float f) {      // RNE float->bf16
    unsigned u = __float_as_uint(f);
    unsigned r = u + 0x7fff + ((u >> 16) & 1);
    return (unsigned short)(r >> 16);
}
__device__ __forceinline__ unsigned fkey(float f) {            // monotone f32->u32
    unsigned u = __float_as_uint(f);
    return (u & 0x80000000u) ? ~u : (u | 0x80000000u);
}
__device__ __forceinline__ unsigned short f2h(float f) {       // RNE float->fp16 bits
    const __half h = __float2half(f);
    return *(const unsigned short*)&h;
}
__device__ __forceinline__ float h2f(unsigned short u) {
    __half_raw r; r.x = u;
    return __half2float((__half)r);
}

// ---------------------------------------------------------------------------
// K1: row-wise L2 normalize for BOTH inputs in one launch.
//  - z rows   -> zn fp32 (d_out scratch) + zb bf16 PLAIN row-major (the LDS
//    staging swizzle is applied via per-lane global addresses in mfma_dist).
//  - emb rows -> en fp32 + esw bf16 swizzled into exact MFMA A-fragment order
//    (frag16=row>>4, kc: 512 ushorts at (frag16*8+kc)*512; within:
//    ((k>>3&3)*16 + (row&15))*8 + (k&7)) + e2.
// ---------------------------------------------------------------------------
__global__ __launch_bounds__(256) void l2norm_all(const float* __restrict__ z,
                                                  const float* __restrict__ emb,
                                                  float* __restrict__ zn,
                                                  unsigned short* __restrict__ zb,
                                                  float* __restrict__ en,
                                                  unsigned short* __restrict__ esw,
                                                  float* __restrict__ e2) {
    const int lane = threadIdx.x & 63;
    const bool isE = blockIdx.x < (N_E / 4);
    const int row = (isE ? blockIdx.x : blockIdx.x - N_E / 4) * 4 + (threadIdx.x >> 6);
    const float* in = isE ? emb : z;
    float* out = isE ? en : zn;
    const float4 v = *(const float4*)(in + row * DIM + lane * 4);
    float s = v.x * v.x + v.y * v.y + v.z * v.z + v.w * v.w;
#pragma unroll
    for (int off = 1; off < 64; off <<= 1) s += __shfl_xor(s, off, 64);
    const float inv = 1.0f / fmaxf(sqrtf(s), 1e-12f);
    const float4 o = make_float4(v.x * inv, v.y * inv, v.z * inv, v.w * inv);
    *(float4*)(out + row * DIM + lane * 4) = o;
    ushort4 ob; ob.x = f2bf(o.x); ob.y = f2bf(o.y); ob.z = f2bf(o.z); ob.w = f2bf(o.w);
    const int k0 = lane * 4;
    if (isE) {
        const size_t sidx = ((size_t)((row >> 4) * 8 + (k0 >> 5)) * 64
                             + ((k0 >> 3) & 3) * 16 + (row & 15)) * 8 + (k0 & 7);
        *(ushort4*)(esw + sidx) = ob;
        float q = o.x * o.x + o.y * o.y + o.z * o.z + o.w * o.w;
#pragma unroll
        for (int off = 1; off < 64; off <<= 1) q += __shfl_xor(q, off, 64);
        if (lane == 0) e2[row] = q;
    } else {
        *(ushort4*)(zb + (size_t)row * DIM + k0) = ob;
    }
}

// ---------------------------------------------------------------------------
// K2: bf16 MFMA distance pass, v6b = STAGE-ONCE / ONE-BARRIER / 4 col-tiles,
// capped at 56 KB LDS (a config that has compiled+run here; v6's 72 KB never
// ran - container failed, possibly static-LDS limit, possibly infra flake).
// Block = 128 z-rows x 512 codes (4 col-tiles of 128); grid 64x16 = 1024.
//  - As[3][128*64] = 48 KB: kc 0..5 staged ONCE with v1's measured-0-conflict
//    per-pair layout + XOR slot swizzle (per-lane global addresses). After
//    ONE barrier, LDS is read-only -> no further syncs; 8 resident waves
//    (2 blocks/CU) drift and overlap MFMA/LDS/VALU. MFMA per staged block
//    x4 vs v5 (2480 cyc/wave) against one cold stage + one barrier.
//  - kc 6,7 z-fragments in REGISTERS (z67[2][4], 32 VGPR), loaded in the
//    prologue from zb at the exact fragment addresses (path validated in
//    round 1: v2 passed with identical bytes). Total regs ~180 < 256.
//  - codes: rolling distance-2 register window; per-phase sched_barrier(0)
//    caps scheduler hoisting across the 32 unrolled phases (v3 spill lesson).
//  - barrier drain: per-wave vm queue = [S x12, Z x8, A x8] -> vmcnt(16)
//    drains all stages, keeps z67/ca in flight (compiler adds its own waits
//    before their register uses).
//  - epilogue per ct: wave-private smw pad (8 KB), regular stores (v4
//    lesson: NT hint = 3x write amplification).
// Numerics: identical MFMA order/operands and epilogue math as v5 (passed,
// absmax 2.4e-4); only the staging/sync schedule changed.
// ---------------------------------------------------------------------------
__global__ __launch_bounds__(256, 2) void mfma_dist(const unsigned short* __restrict__ zb,
                                                    const unsigned short* __restrict__ esw,
                                                    unsigned short* __restrict__ segMh) {
    __shared__ __align__(16) unsigned short As[3][128 * 64];   // 48 KB: kc 0..5
    __shared__ float smw[4][8][64];                            // 8 KB wave-private pads

    const int tid  = threadIdx.x;
    const int lane = tid & 63;
    const int wave = tid >> 6;
    const int wm = wave & 1, wn = wave >> 1;
    const int rb = blockIdx.x & 63;          // row block (128 rows)
    const int cb = blockIdx.x >> 6;          // col group (512 codes)
    const int row0 = rb * 128;
    const int fr = lane & 15, q = lane >> 4;

    // Code fragments: frag16 = cb*32 + ct*8 + wn*4 + i; m = ct*8 + kc.
    const unsigned short* ebase = esw + (size_t)(cb * 32 + wn * 4) * 4096 + lane * 8;
    auto la = [&](int m, int i) {
        return *(const bf16x8*)(ebase + (size_t)((m >> 3) * 8 + i) * 4096 + (m & 7) * 512);
    };
    // z staging, pair p (k in [p*64,p*64+64)) -> buffer As[p], p = 0..2;
    // wave stages rows wave*32..+31, 4 instrs of 1 KB; slot XOR baked into
    // the per-lane GLOBAL address (cxor); identical layout as v1/v5.
    const int cxor = (lane & 7) ^ ((lane >> 3) & 7);            // const per lane
    const unsigned short* gZ = zb + (size_t)(row0 + wave * 32 + (lane >> 3)) * DIM + cxor * 8;
#pragma unroll
    for (int p = 0; p < 3; p++)
#pragma unroll
        for (int j = 0; j < 4; j++)
            __builtin_amdgcn_global_load_lds(
                (const __attribute__((address_space(1))) unsigned int*)(gZ + (size_t)j * 8 * DIM + p * 64),
                (__attribute__((address_space(3))) unsigned int*)&As[p][(wave * 32 + j * 8) * 64],
                16, 0, 0);
    __builtin_amdgcn_sched_barrier(0);       // pin: 12 stages first in vm queue
    // kc 6,7 z-fragments -> registers, reused across all 4 col-tiles.
    // Row wm*64+i*16+fr, k = kc*32 + q*8 (same bytes the LDS path delivers).
    bf16x8 z67[2][4];
#pragma unroll
    for (int h = 0; h < 2; h++)
#pragma unroll
        for (int i = 0; i < 4; i++)
            z67[h][i] = *(const bf16x8*)(zb + (size_t)(row0 + wm * 64 + i * 16 + fr) * DIM
                                         + (6 + h) * 32 + q * 8);
    __builtin_amdgcn_sched_barrier(0);       // then the 8 z67 loads
    bf16x8 ca[8][4];
#pragma unroll
    for (int m = 0; m < 2; m++)
#pragma unroll
        for (int i = 0; i < 4; i++) ca[m][i] = la(m, i);
    __builtin_amdgcn_sched_barrier(0);       // then the 8 ca loads
    // Queue/wave: [S x12, Z x8, A x8] -> vmcnt(16) drains all stages only.
    asm volatile("s_waitcnt vmcnt(16)" ::: "memory");
    __builtin_amdgcn_s_barrier();            // the ONLY barrier
    __builtin_amdgcn_sched_barrier(0);

    // z fragment kc 0..5: buffer kc>>1, h = kc&1; slot = (h*4+q)^(fr&7)
    // -> 8 lanes per 16B slot = conflict-free (v1/v5: 0 measured).
    auto lz = [&](int kc, int i) {
        const int r = wm * 64 + i * 16 + fr;
        const int slot = ((kc & 1) * 4 + q) ^ (fr & 7);
        return *(const bf16x8*)&As[kc >> 1][r * 64 + slot * 8];
    };

#pragma unroll
    for (int ct = 0; ct < 4; ct++) {
        f32x4 acc[4][4];
#pragma unroll
        for (int ci = 0; ci < 4; ci++)
#pragma unroll
            for (int zi = 0; zi < 4; zi++) acc[ci][zi] = (f32x4){0.f, 0.f, 0.f, 0.f};

#pragma unroll
        for (int kc = 0; kc < 8; kc++) {
            const int m = ct * 8 + kc;
            if (m + 2 < 32) {                // rolling refill, distance 2
#pragma unroll
                for (int i = 0; i < 4; i++) ca[(m + 2) & 7][i] = la(m + 2, i);
            }
            bf16x8 zfr[4];
#pragma unroll
            for (int i = 0; i < 4; i++)
                zfr[i] = (kc < 6) ? lz(kc, i) : z67[kc - 6][i];
#pragma unroll
            for (int ci = 0; ci < 4; ci++)
#pragma unroll
                for (int zi = 0; zi < 4; zi++)
                    acc[ci][zi] = __builtin_amdgcn_mfma_f32_16x16x32_bf16(ca[kc][ci], zfr[zi], acc[ci][zi], 0, 0, 0);
            __builtin_amdgcn_sched_barrier(0);   // cap hoisting across phases
        }

        // Per-wave epilogue (no block sync). C/D: m(code)=(lane>>4)*4+reg,
        // n(z row)=lane&15. d = 1.0 - 2*dot (codes unit-norm).
#pragma unroll
        for (int ci = 0; ci < 4; ci++) {
#pragma unroll
            for (int zi = 0; zi < 4; zi++) {
                const float t0 = fmaf(-2.0f, acc[ci][zi][0], 1.0f);
                const float t1 = fmaf(-2.0f, acc[ci][zi][1], 1.0f);
                const float t2 = fmaf(-2.0f, acc[ci][zi][2], 1.0f);
                const float t3 = fmaf(-2.0f, acc[ci][zi][3], 1.0f);
                float mm = fminf(fminf(t0, t1), fminf(t2, t3));   // min over 4 codes
                mm = fminf(mm, __shfl_xor(mm, 16, 64));           // pair quads: 8-code min
                if (q == 0) smw[wave][ci * 2 + 0][zi * 16 + fr] = mm;
                if (q == 2) smw[wave][ci * 2 + 1][zi * 16 + fr] = mm;
            }
        }
        // Transpose out of the wave-private pad: lane = local row, 8 segs.
        ushort8 o8;
#pragma unroll
        for (int j = 0; j < 8; j++) o8[j] = f2h(smw[wave][j][lane]);
        *(ushort8*)&segMh[(size_t)(row0 + wm * 64 + lane) * NSEG + cb * 64 + ct * 16 + wn * 8] = o8;
    }
}

// ---------------------------------------------------------------------------
// K3 (fused select+rescore+gather): one WAVE per row, ZERO atomics.
//  1. read 1024 fp16 group-mins (2 KB contiguous), shuffle-min -> threshold
//  2. ballot-flag 8-col groups within m+MARGIN (winner always self-flags)
//  3. wave-uniform bit-walk, TWO groups per iteration (16 float4 gathers in
//     flight -> halves the serial L2/L3-latency chain); exact fp32 rescore
//     (16 lanes split the 256-dim dot, 4 cols per pass); packed (key|col)
//     running min -> exact argmin, lowest-index tie-break (jnp.argmin);
//     min-reduction is order-independent so dual-issue preserves semantics.
//  4. gather en[idx] -> z_q, per-row loss partial to pl[row], index out.
// ---------------------------------------------------------------------------
__global__ __launch_bounds__(256) void select_rescore(const unsigned short* __restrict__ segMh,
                                                      const float* __restrict__ en,
                                                      const float* __restrict__ e2,
                                                      float* zq,        // d_out: z_norm in / z_q out
                                                      float* out_base,  // d_out
                                                      float* __restrict__ pl) {
    const int lane = threadIdx.x & 63;
    const int row  = (blockIdx.x << 2) + (threadIdx.x >> 6);
    const unsigned short* ph = segMh + (size_t)row * NSEG + lane * 16;
    const ushort8 u0 = *(const ushort8*)ph;
    const ushort8 u1 = *(const ushort8*)(ph + 8);
    float vv[16];
#pragma unroll
    for (int j = 0; j < 8; j++) { vv[j] = h2f(u0[j]); vv[8 + j] = h2f(u1[j]); }
    float m = vv[0];
#pragma unroll
    for (int j = 1; j < 16; j++) m = fminf(m, vv[j]);
#pragma unroll
    for (int off = 1; off < 64; off <<= 1) m = fminf(m, __shfl_xor(m, off, 64));
    const float thr = m + MARGIN;

    // z row in 16-lane-split layout for the rescore dots (shared by all groups)
    const int q = lane >> 4, f = lane & 15;
    const float4* zp = (const float4*)(zq + (size_t)row * DIM);
    float4 z4[4];
#pragma unroll
    for (int j = 0; j < 4; j++) z4[j] = zp[j * 16 + f];

    unsigned long long pk = ~0ull;
#pragma unroll
    for (int j = 0; j < 16; j++) {
        unsigned long long bal = __ballot(vv[j] <= thr);   // wave-uniform
        while (bal) {
            const int l1 = __ffsll(bal) - 1; bal &= bal - 1;
            int l2 = l1;
            if (bal) { l2 = __ffsll(bal) - 1; bal &= bal - 1; }  // dup if odd (harmless)
            const int segA = l1 * 16 + j, segB = l2 * 16 + j;
            const int cA0 = segA * 8 + q,     cA1 = segA * 8 + 4 + q;
            const int cB0 = segB * 8 + q,     cB1 = segB * 8 + 4 + q;
            const float4* pA0 = (const float4*)(en + (size_t)cA0 * DIM);
            const float4* pA1 = (const float4*)(en + (size_t)cA1 * DIM);
            const float4* pB0 = (const float4*)(en + (size_t)cB0 * DIM);
            const float4* pB1 = (const float4*)(en + (size_t)cB1 * DIM);
            float4 eA0[4], eA1[4], eB0[4], eB1[4];
#pragma unroll
            for (int jj = 0; jj < 4; jj++) {              // 16 loads in flight
                eA0[jj] = pA0[jj * 16 + f]; eA1[jj] = pA1[jj * 16 + f];
                eB0[jj] = pB0[jj * 16 + f]; eB1[jj] = pB1[jj * 16 + f];
            }
            float sA0 = 0.f, sA1 = 0.f, sB0 = 0.f, sB1 = 0.f;
#pragma unroll
            for (int jj = 0; jj < 4; jj++) {
                sA0 = fmaf(z4[jj].x, eA0[jj].x, sA0); sA0 = fmaf(z4[jj].y, eA0[jj].y, sA0);
                sA0 = fmaf(z4[jj].z, eA0[jj].z, sA0); sA0 = fmaf(z4[jj].w, eA0[jj].w, sA0);
                sA1 = fmaf(z4[jj].x, eA1[jj].x, sA1); sA1 = fmaf(z4[jj].y, eA1[jj].y, sA1);
                sA1 = fmaf(z4[jj].z, eA1[jj].z, sA1); sA1 = fmaf(z4[jj].w, eA1[jj].w, sA1);
                sB0 = fmaf(z4[jj].x, eB0[jj].x, sB0); sB0 = fmaf(z4[jj].y, eB0[jj].y, sB0);
                sB0 = fmaf(z4[jj].z, eB0[jj].z, sB0); sB0 = fmaf(z4[jj].w, eB0[jj].w, sB0);
                sB1 = fmaf(z4[jj].x, eB1[jj].x, sB1); sB1 = fmaf(z4[jj].y, eB1[jj].y, sB1);
                sB1 = fmaf(z4[jj].z, eB1[jj].z, sB1); sB1 = fmaf(z4[jj].w, eB1[jj].w, sB1);
            }
#pragma unroll
            for (int off = 1; off < 16; off <<= 1) {
                sA0 += __shfl_xor(sA0, off, 64); sA1 += __shfl_xor(sA1, off, 64);
                sB0 += __shfl_xor(sB0, off, 64); sB1 += __shfl_xor(sB1, off, 64);
            }
            const float dA0 = fmaf(-2.0f, sA0, e2[cA0]);
            const float dA1 = fmaf(-2.0f, sA1, e2[cA1]);
            const float dB0 = fmaf(-2.0f, sB0, e2[cB0]);
            const float dB1 = fmaf(-2.0f, sB1, e2[cB1]);
            unsigned long long k;
            k = ((unsigned long long)fkey(dA0) << 32) | (unsigned)cA0; if (k < pk) pk = k;
            k = ((unsigned long long)fkey(dA1) << 32) | (unsigned)cA1; if (k < pk) pk = k;
            k = ((unsigned long long)fkey(dB0) << 32) | (unsigned)cB0; if (k < pk) pk = k;
            k = ((unsigned long long)fkey(dB1) << 32) | (unsigned)cB1; if (k < pk) pk = k;
        }
    }
#pragma unroll
    for (int off = 16; off < 64; off <<= 1) {               // merge the 4 quads
        const unsigned long long o = __shfl_xor(pk, off, 64);
        if (o < pk) pk = o;
    }
    const int i = (int)(pk & 0xffffffffu);

    // Gather z_q, loss partial, index (plain stores, no atomics).
    const float4 qv = *(const float4*)(en + (size_t)i * DIM + lane * 4);
    const float4 zv = *(const float4*)(zq + (size_t)row * DIM + lane * 4);
    const float dx = qv.x - zv.x, dy = qv.y - zv.y, dz = qv.z - zv.z, dw = qv.w - zv.w;
    float s = dx * dx + dy * dy + dz * dz + dw * dw;
    *(float4*)(zq + (size_t)row * DIM + lane * 4) = qv;
#pragma unroll
    for (int off = 1; off < 64; off <<= 1) s += __shfl_xor(s, off, 64);
    if (lane == 0) {
        pl[row] = s;
        out_base[N_TOK * DIM + 1 + row] = (float)i;
    }
}

// ---------------------------------------------------------------------------
// K4: reduce 8192 per-row loss partials -> loss = 1.25 * sum / (8*1024*256).
// ---------------------------------------------------------------------------
__global__ __launch_bounds__(1024) void finalize_loss(const float* __restrict__ pl,
                                                      float* __restrict__ out) {
    __shared__ float sw[16];
    const int t = threadIdx.x;
    float s = 0.f;
#pragma unroll
    for (int j = 0; j < 8; j++) s += pl[t + j * 1024];
#pragma unroll
    for (int off = 1; off < 64; off <<= 1) s += __shfl_xor(s, off, 64);
    if ((t & 63) == 0) sw[t >> 6] = s;
    __syncthreads();
    if (t < 16) {
        float v = sw[t];
#pragma unroll
        for (int off = 1; off < 16; off <<= 1) v += __shfl_xor(v, off, 64);
        if (t == 0) out[N_TOK * DIM] = v * (1.25f / 2097152.0f);
    }
}

// ---------------------------------------------------------------------------
extern "C" void kernel_launch(void* const* d_in, const int* in_sizes, int n_in,
                              void* d_out, int out_size, void* d_ws, size_t ws_size,
                              hipStream_t stream) {
    const float* z   = (const float*)d_in[0];   // [8,1024,256] fp32
    const float* emb = (const float*)d_in[1];   // [8192,256] fp32
    float* out = (float*)d_out;                 // z_q[2097152] | loss[1] | idx[8192]
    char* ws = (char*)d_ws;

    // ws layout (byte offsets; total ~33.6 MB)
    float*          en    = (float*)(ws);                      //  8 MiB fp32 codes (normalized)
    unsigned short* esw   = (unsigned short*)(ws + 8388608);   //  4 MiB bf16 codes (frag-swizzled)
    unsigned short* zb    = (unsigned short*)(ws + 12582912);  //  4 MiB bf16 z (plain row-major)
    float*          e2    = (float*)(ws + 16777216);           // 32 KiB ||e||^2
    unsigned short* segMh = (unsigned short*)(ws + 16809984);  // 16 MiB fp16 [8192][1024]
    float*          pl    = (float*)(ws + 33587200);           // 32 KiB per-row loss partials

    // 1) normalize both inputs (emb -> en/esw/e2; z -> d_out z_q region + zb)
    l2norm_all<<<(N_E + N_TOK) / 4, 256, 0, stream>>>(z, emb, out, zb, en, esw, e2);
    // 2) bf16 MFMA approx distances (stage-once, ONE barrier, 4 col-tiles)
    mfma_dist<<<1024, 256, 0, stream>>>(zb, esw, segMh);
    // 3) fused select + exact rescore + gather (wave per row, dual-group walk)
    select_rescore<<<N_TOK / 4, 256, 0, stream>>>(segMh, en, e2, out, out, pl);
    // 4) reduce loss partials
    finalize_loss<<<1, 1024, 0, stream>>>(pl, out);
}